// Round 11
// baseline (6642.545 us; speedup 1.0000x reference)
//
#include <hip/hip_runtime.h>

#define NPTS 2048
#define BATCH 8
#define KNN 20

// ---------------------------------------------------------------------------
// Model (R0-R10): ref = np transcription with einsum->BLAS sgemm (per-element
// ascending FMA chains), sq = multiply-temp + numpy pairwise non-FMA sum,
// d = (2e - sqn) - sqm left-assoc f32, top-k desc ties->lower index,
// conv = single FMA chain over concatenated 2C h-vector, BN f32 left-assoc.
// Selection ranks on our f32 D (bit-matching ref's d under this model).

// ---------------------------------------------------------------------------
// sq, C==3: products rounded individually, sequential sum (numpy n<8).
__global__ void k_sqnorm3(const float* __restrict__ fin, int stride, int off,
                          float* __restrict__ sq) {
  int i = blockIdx.x * 256 + threadIdx.x;
  const float* r = fin + (size_t)i * stride + off;
  float p0 = __fmul_rn(r[0], r[0]);
  float p1 = __fmul_rn(r[1], r[1]);
  float p2 = __fmul_rn(r[2], r[2]);
  sq[i] = __fadd_rn(__fadd_rn(p0, p1), p2);
}

// sq, C=64/128 (<=128): numpy pairwise 8-accumulator pattern, non-FMA:
// r[j]=p[j]; for i=8..C-8 step 8: r[j]+=p[i+j]; res=((r0+r1)+(r2+r3))+((r4+r5)+(r6+r7)).
template <int C>
__global__ void k_sqnorm_pw(const float* __restrict__ fin, int stride, int off,
                            float* __restrict__ sq) {
  int i = blockIdx.x * 256 + threadIdx.x;
  const float* r = fin + (size_t)i * stride + off;
  float a8[8];
  #pragma unroll
  for (int j = 0; j < 8; ++j) a8[j] = __fmul_rn(r[j], r[j]);
  #pragma unroll
  for (int ii = 8; ii < C; ii += 8)
    #pragma unroll
    for (int j = 0; j < 8; ++j)
      a8[j] = __fadd_rn(a8[j], __fmul_rn(r[ii + j], r[ii + j]));
  sq[i] = __fadd_rn(__fadd_rn(__fadd_rn(a8[0], a8[1]), __fadd_rn(a8[2], a8[3])),
                    __fadd_rn(__fadd_rn(a8[4], a8[5]), __fadd_rn(a8[6], a8[7])));
}

// ---------------------------------------------------------------------------
// Screen GEMM (sgemm-emulating): per-element single fmaf chain ascending k;
// D = (2e - sqn) - sqm left-assoc. 2 batches per dispatch.
__global__ void __launch_bounds__(256) k_screen(const float* __restrict__ fin,
                                                int stride, int off, int KK,
                                                const float* __restrict__ sq,
                                                int bbase, float* __restrict__ Dbase) {
  __shared__ float As[16][68];
  __shared__ float Bs[16][68];
  int tid = threadIdx.x;
  int b = bbase + blockIdx.z;
  float* D = Dbase + (size_t)blockIdx.z * NPTS * NPTS;
  int n0 = blockIdx.y * 64, m0 = blockIdx.x * 64;
  const float* fb = fin + (size_t)b * NPTS * stride + off;
  int lr = tid >> 2;            // 0..63
  int lk = (tid & 3) * 4;       // 0,4,8,12
  float acc[4][4];
  #pragma unroll
  for (int i = 0; i < 4; ++i)
    #pragma unroll
    for (int j = 0; j < 4; ++j) acc[i][j] = 0.f;
  for (int k0 = 0; k0 < KK; k0 += 16) {
    float4 av, bv;
    const float* arow = fb + (size_t)(n0 + lr) * stride + k0 + lk;
    const float* brow = fb + (size_t)(m0 + lr) * stride + k0 + lk;
    int rem = KK - k0;
    if (lk + 4 <= rem) { av = *(const float4*)arow; bv = *(const float4*)brow; }
    else {
      av.x = (lk + 0 < rem) ? arow[0] : 0.f;  bv.x = (lk + 0 < rem) ? brow[0] : 0.f;
      av.y = (lk + 1 < rem) ? arow[1] : 0.f;  bv.y = (lk + 1 < rem) ? brow[1] : 0.f;
      av.z = (lk + 2 < rem) ? arow[2] : 0.f;  bv.z = (lk + 2 < rem) ? brow[2] : 0.f;
      av.w = (lk + 3 < rem) ? arow[3] : 0.f;  bv.w = (lk + 3 < rem) ? brow[3] : 0.f;
    }
    __syncthreads();
    As[lk+0][lr] = av.x; As[lk+1][lr] = av.y; As[lk+2][lr] = av.z; As[lk+3][lr] = av.w;
    Bs[lk+0][lr] = bv.x; Bs[lk+1][lr] = bv.y; Bs[lk+2][lr] = bv.z; Bs[lk+3][lr] = bv.w;
    __syncthreads();
    int ty = tid >> 4, tx = tid & 15;
    #pragma unroll
    for (int kk = 0; kk < 16; ++kk) {
      float4 a = *(const float4*)&As[kk][ty * 4];
      float4 b2 = *(const float4*)&Bs[kk][tx * 4];
      acc[0][0] = fmaf(a.x, b2.x, acc[0][0]); acc[0][1] = fmaf(a.x, b2.y, acc[0][1]);
      acc[0][2] = fmaf(a.x, b2.z, acc[0][2]); acc[0][3] = fmaf(a.x, b2.w, acc[0][3]);
      acc[1][0] = fmaf(a.y, b2.x, acc[1][0]); acc[1][1] = fmaf(a.y, b2.y, acc[1][1]);
      acc[1][2] = fmaf(a.y, b2.z, acc[1][2]); acc[1][3] = fmaf(a.y, b2.w, acc[1][3]);
      acc[2][0] = fmaf(a.z, b2.x, acc[2][0]); acc[2][1] = fmaf(a.z, b2.y, acc[2][1]);
      acc[2][2] = fmaf(a.z, b2.z, acc[2][2]); acc[2][3] = fmaf(a.z, b2.w, acc[2][3]);
      acc[3][0] = fmaf(a.w, b2.x, acc[3][0]); acc[3][1] = fmaf(a.w, b2.y, acc[3][1]);
      acc[3][2] = fmaf(a.w, b2.z, acc[3][2]); acc[3][3] = fmaf(a.w, b2.w, acc[3][3]);
    }
  }
  int ty = tid >> 4, tx = tid & 15;
  const float* sqb = sq + b * NPTS;
  #pragma unroll
  for (int i = 0; i < 4; ++i) {
    float sn = sqb[n0 + ty * 4 + i];
    #pragma unroll
    for (int j = 0; j < 4; ++j) {
      float d = __fsub_rn(__fsub_rn(__fmul_rn(2.f, acc[i][j]), sn), sqb[m0 + tx * 4 + j]);
      D[(size_t)(n0 + ty * 4 + i) * NPTS + m0 + tx * 4 + j] = d;
    }
  }
}

// ---------------------------------------------------------------------------
__device__ inline unsigned f2u(float f) {
  unsigned b = __float_as_uint(f);
  return b ^ (unsigned)(((int)b >> 31) | 0x80000000);
}

// top-20 on f32 D: desc, ties -> lower index.
__device__ inline void row_select(const float (&dv)[32], int wt,
                                  int*   __restrict__ candc,   // [256]
                                  float* __restrict__ candf,   // [256]
                                  int* __restrict__ outp) {
  unsigned u[32];
  #pragma unroll
  for (int s = 0; s < 32; ++s) u[s] = f2u(dv[s]);
  unsigned P = 0u;
  for (int k = 31; k >= 8; --k) {
    unsigned Pt = P | (1u << k);
    int bc = 0;
    #pragma unroll
    for (int s = 0; s < 32; ++s) bc += (u[s] >= Pt) ? 1 : 0;
    #pragma unroll
    for (int o = 1; o < 64; o <<= 1) bc += __shfl_xor(bc, o, 64);
    if (bc >= 32) P = Pt;
  }
  const unsigned T = P;
  int cnt = 0;
  #pragma unroll
  for (int s = 0; s < 32; ++s) {
    bool pred = (u[s] >= T);
    unsigned long long mk = __ballot(pred);
    if (pred) {
      int pos = cnt + (int)__popcll(mk & ((1ull << wt) - 1ull));
      if (pos < 256) {
        candc[pos] = ((s >> 2) << 8) + (wt << 2) + (s & 3);
        candf[pos] = dv[s];
      }
    }
    cnt += (int)__popcll(mk);
  }
  if (cnt > 256) cnt = 256;
  __threadfence_block();
  #pragma unroll
  for (int q = 0; q < 4; ++q) {
    int ci = wt + 64 * q;
    if (ci < cnt) {
      int   mq = candc[ci];
      float dq = candf[ci];
      int r = 0;
      for (int j = 0; j < cnt; ++j) {
        float dj = candf[j]; int mj = candc[j];
        r += (dj > dq || (dj == dq && mj < mq)) ? 1 : 0;
      }
      if (r < KNN) outp[r] = mq;
    }
  }
}

__global__ void __launch_bounds__(256) k_select(const float* __restrict__ Dbase,
                                                int bbase, int* __restrict__ idxo) {
  __shared__ int   candcS[4][256];
  __shared__ float candfS[4][256];
  int tid = threadIdx.x;
  int wave = tid >> 6, wt = tid & 63;
  int b = bbase + blockIdx.y;
  const float* D = Dbase + (size_t)blockIdx.y * NPTS * NPTS;
  int n = blockIdx.x * 4 + wave;
  float dv[32];
  const float4* rp = (const float4*)(D + (size_t)n * NPTS) + wt;
  #pragma unroll
  for (int j = 0; j < 8; ++j) {
    float4 v = rp[64 * j];
    dv[j*4+0] = v.x; dv[j*4+1] = v.y; dv[j*4+2] = v.z; dv[j*4+3] = v.w;
  }
  row_select(dv, wt, candcS[wave], candfS[wave],
             idxo + ((size_t)b * NPTS + n) * KNN);
}

// ---------------------------------------------------------------------------
// Edge-conv, sgemm-emulating: per (n,k,f): y = single fmaf chain ascending
// over 2C of h=[x_m - x_n, x_n] (contiguous concat) with w[f] (raw layout).
// Per (n,f): max/min over k by sign(g) (BN monotone in f32), f64 stats.
template <int C, int F>
__global__ void __launch_bounds__(256) k_econv(const float* __restrict__ fin,
                                               int stride, int off,
                                               const int* __restrict__ idx,
                                               const float* __restrict__ w,
                                               const float* __restrict__ g,
                                               float* __restrict__ cat, int catoff,
                                               double* __restrict__ stats) {
  const int TC = 2 * C;
  __shared__ float hS[20][2 * C + 4];
  __shared__ float wS[32][2 * C + 4];
  __shared__ float xnS[C];
  int tid = threadIdx.x;
  int n = blockIdx.x;
  int f0 = blockIdx.y * 32;
  int gbase = n & ~(NPTS - 1);
  for (int c = tid; c < C; c += 256) xnS[c] = fin[(size_t)n * stride + off + c];
  __syncthreads();
  for (int i = tid; i < 20 * C; i += 256) {
    int k = i / C, c = i - k * C;
    int m = idx[n * KNN + k];
    float xm = fin[(size_t)(gbase + m) * stride + off + c];
    hS[k][c] = __fsub_rn(xm, xnS[c]);
    hS[k][C + c] = xnS[c];
  }
  for (int i = tid; i < 32 * TC; i += 256) {
    int fr = i / TC, c = i - fr * TC;
    wS[fr][c] = w[(size_t)(f0 + fr) * TC + c];
  }
  __syncthreads();
  int f = tid >> 3, kl = tid & 7;      // 32 f x 8 k-lanes
  float mx = -1e30f, mn = 1e30f;
  double s = 0.0, ss = 0.0;
  for (int k = kl; k < KNN; k += 8) {
    float y = 0.f;
    #pragma unroll 8
    for (int c = 0; c < TC; ++c)
      y = fmaf(hS[k][c], wS[f][c], y);
    mx = fmaxf(mx, y); mn = fminf(mn, y);
    double yd = (double)y;
    s += yd; ss = fma(yd, yd, ss);
  }
  #pragma unroll
  for (int o = 4; o > 0; o >>= 1) {
    mx = fmaxf(mx, __shfl_down(mx, o, 8));
    mn = fminf(mn, __shfl_down(mn, o, 8));
    s += __shfl_down(s, o, 8);
    ss += __shfl_down(ss, o, 8);
  }
  if (kl == 0) {
    float gg = g[f0 + f];
    cat[(size_t)n * 512 + catoff + f0 + f] = (gg >= 0.f) ? mx : mn;
    atomicAdd(&stats[f0 + f], s);
    atomicAdd(&stats[F + f0 + f], ss);
  }
}

// BN + leaky on CAT slice: f64 stats, f32 left-assoc application:
// t = ((g*(y-mean))*rs) + b; leaky 0.2f*t.
__global__ void k_bn(float* __restrict__ cat, const double* __restrict__ stats,
                     const float* __restrict__ g, const float* __restrict__ bb,
                     int Fbits, int catoff) {
  int i = blockIdx.x * 256 + threadIdx.x;
  int F = 1 << Fbits;
  int f = i & (F - 1);
  int bn = i >> Fbits;
  const double invCnt = 1.0 / (double)(BATCH * NPTS * KNN);
  double mean64 = stats[f] * invCnt;
  double ex2 = stats[F + f] * invCnt;
  double var64 = ex2 - mean64 * mean64;
  if (var64 < 0.0) var64 = 0.0;
  float mean32 = (float)mean64;
  float vs = (float)var64;
  float rs = 1.0f / __fsqrt_rn(__fadd_rn(vs, 1e-5f));
  float* p = &cat[(size_t)bn * 512 + catoff + f];
  float y = *p;
  float u = __fmul_rn(g[f], __fsub_rn(y, mean32));
  float t = __fadd_rn(__fmul_rn(u, rs), bb[f]);
  *p = (t >= 0.f) ? t : __fmul_rn(0.2f, t);
}

// ---------------------------------------------------------------------------
// Final GEMM (values only; threshold-covered): CAT @ wf^T -> out f32.
__global__ void __launch_bounds__(256) k_gemm(const float* __restrict__ A,
                                              const float* __restrict__ Bw,
                                              float* __restrict__ Cc) {
  __shared__ float As[16][68];
  __shared__ float Bs[16][68];
  int tid = threadIdx.x;
  int m0 = blockIdx.y * 64, f0 = blockIdx.x * 64;
  int ty = tid >> 4, tx = tid & 15;
  int lr = tid >> 2;
  int lk = (tid & 3) * 4;
  float acc[4][4];
  #pragma unroll
  for (int i = 0; i < 4; ++i)
    #pragma unroll
    for (int j = 0; j < 4; ++j) acc[i][j] = 0.f;
  for (int k0 = 0; k0 < 512; k0 += 16) {
    float4 av = *(const float4*)&A [(size_t)(m0 + lr) * 512 + k0 + lk];
    float4 bv = *(const float4*)&Bw[(size_t)(f0 + lr) * 512 + k0 + lk];
    __syncthreads();
    As[lk+0][lr] = av.x; As[lk+1][lr] = av.y; As[lk+2][lr] = av.z; As[lk+3][lr] = av.w;
    Bs[lk+0][lr] = bv.x; Bs[lk+1][lr] = bv.y; Bs[lk+2][lr] = bv.z; Bs[lk+3][lr] = bv.w;
    __syncthreads();
    #pragma unroll
    for (int kk = 0; kk < 16; ++kk) {
      float4 a = *(const float4*)&As[kk][ty * 4];
      float4 b = *(const float4*)&Bs[kk][tx * 4];
      acc[0][0] = fmaf(a.x, b.x, acc[0][0]); acc[0][1] = fmaf(a.x, b.y, acc[0][1]);
      acc[0][2] = fmaf(a.x, b.z, acc[0][2]); acc[0][3] = fmaf(a.x, b.w, acc[0][3]);
      acc[1][0] = fmaf(a.y, b.x, acc[1][0]); acc[1][1] = fmaf(a.y, b.y, acc[1][1]);
      acc[1][2] = fmaf(a.y, b.z, acc[1][2]); acc[1][3] = fmaf(a.y, b.w, acc[1][3]);
      acc[2][0] = fmaf(a.z, b.x, acc[2][0]); acc[2][1] = fmaf(a.z, b.y, acc[2][1]);
      acc[2][2] = fmaf(a.z, b.z, acc[2][2]); acc[2][3] = fmaf(a.z, b.w, acc[2][3]);
      acc[3][0] = fmaf(a.w, b.x, acc[3][0]); acc[3][1] = fmaf(a.w, b.y, acc[3][1]);
      acc[3][2] = fmaf(a.w, b.z, acc[3][2]); acc[3][3] = fmaf(a.w, b.w, acc[3][3]);
    }
  }
  #pragma unroll
  for (int i = 0; i < 4; ++i)
    #pragma unroll
    for (int j = 0; j < 4; ++j)
      Cc[(size_t)(m0 + ty * 4 + i) * 1024 + f0 + tx * 4 + j] = acc[i][j];
}

__global__ void k_fstats(const float* __restrict__ y, double* __restrict__ st) {
  int tid = threadIdx.x;
  int r0 = blockIdx.x * 256;
  double s[4] = {0,0,0,0}, ss[4] = {0,0,0,0};
  for (int r = r0; r < r0 + 256; ++r) {
    const float* row = y + (size_t)r * 1024;
    #pragma unroll
    for (int q = 0; q < 4; ++q) {
      double v = (double)row[tid + 256 * q];
      s[q] += v; ss[q] = fma(v, v, ss[q]);
    }
  }
  #pragma unroll
  for (int q = 0; q < 4; ++q) {
    atomicAdd(&st[tid + 256 * q], s[q]);
    atomicAdd(&st[1024 + tid + 256 * q], ss[q]);
  }
}

__global__ void k_fnorm(float* __restrict__ y, const double* __restrict__ st,
                        const float* __restrict__ g, const float* __restrict__ bb) {
  int i = blockIdx.x * 256 + threadIdx.x;
  int f = i & 1023;
  const double invCnt = 1.0 / 16384.0;
  double mean = st[f] * invCnt;
  double ex2  = st[1024 + f] * invCnt;
  double var  = ex2 - mean * mean;
  if (var < 0.0) var = 0.0;
  double rs   = rsqrt(var + 1e-5);
  float v = y[i];
  float t = (float)((double)g[f] * ((double)v - mean) * rs + (double)bb[f]);
  y[i] = (t >= 0.f) ? t : 0.2f * t;
}

// ---------------------------------------------------------------------------
extern "C" void kernel_launch(void* const* d_in, const int* in_sizes, int n_in,
                              void* d_out, int out_size, void* d_ws, size_t ws_size,
                              hipStream_t stream) {
  const float* x  = (const float*)d_in[0];
  const float* W[4]  = {(const float*)d_in[1], (const float*)d_in[4],
                        (const float*)d_in[7], (const float*)d_in[10]};
  const float* G[4]  = {(const float*)d_in[2], (const float*)d_in[5],
                        (const float*)d_in[8], (const float*)d_in[11]};
  const float* Bb[4] = {(const float*)d_in[3], (const float*)d_in[6],
                        (const float*)d_in[9], (const float*)d_in[12]};
  const float* wf = (const float*)d_in[13];
  const float* gf = (const float*)d_in[14];
  const float* bf = (const float*)d_in[15];
  float* out = (float*)d_out;

  // workspace: SQ, CAT, ZT (D scratch), ST (f64 stats), IDX.
  float* ws  = (float*)d_ws;
  float* SQ  = ws;                 // 16384 f
  float* CAT = SQ + 16384;         // 8,388,608 f
  float* ZT  = CAT + 8388608;      // 8,388,608 f (D scratch, 2 batches)
  double* ST = (double*)(ZT + 8388608);    // 2048 d
  int*   IDX = (int*)(ST + 2048);  // 16384*20 ints

  const int Cs[4]      = {3, 64, 64, 128};
  const int Fs[4]      = {64, 64, 128, 256};
  const int Fbits[4]   = {6, 6, 7, 8};
  const int offs[4]    = {0, 0, 64, 128};
  const int strides[4] = {3, 512, 512, 512};
  const int catoffs[4] = {0, 64, 128, 256};

  for (int l = 0; l < 4; ++l) {
    const float* fin = (l == 0) ? x : CAT;
    int C = Cs[l], F = Fs[l];
    switch (C) {
      case 3:   k_sqnorm3<<<dim3(64), 256, 0, stream>>>(fin, strides[l], offs[l], SQ); break;
      case 64:  k_sqnorm_pw<64><<<dim3(64), 256, 0, stream>>>(fin, strides[l], offs[l], SQ); break;
      default:  k_sqnorm_pw<128><<<dim3(64), 256, 0, stream>>>(fin, strides[l], offs[l], SQ); break;
    }
    for (int bb = 0; bb < BATCH; bb += 2) {
      k_screen<<<dim3(NPTS / 64, NPTS / 64, 2), 256, 0, stream>>>(fin, strides[l], offs[l], C, SQ, bb, ZT);
      k_select<<<dim3(NPTS / 4, 2), 256, 0, stream>>>(ZT, bb, IDX);
    }
    (void)hipMemsetAsync(ST, 0, 2 * F * sizeof(double), stream);
    switch (l) {
      case 0: k_econv<3, 64>   <<<dim3(16384, 2), 256, 0, stream>>>(fin, strides[l], offs[l], IDX, W[l], G[l], CAT, catoffs[l], ST); break;
      case 1: k_econv<64, 64>  <<<dim3(16384, 2), 256, 0, stream>>>(fin, strides[l], offs[l], IDX, W[l], G[l], CAT, catoffs[l], ST); break;
      case 2: k_econv<64, 128> <<<dim3(16384, 4), 256, 0, stream>>>(fin, strides[l], offs[l], IDX, W[l], G[l], CAT, catoffs[l], ST); break;
      default: k_econv<128, 256><<<dim3(16384, 8), 256, 0, stream>>>(fin, strides[l], offs[l], IDX, W[l], G[l], CAT, catoffs[l], ST); break;
    }
    k_bn<<<dim3(BATCH * NPTS * F / 256), 256, 0, stream>>>(CAT, ST, G[l], Bb[l], Fbits[l], catoffs[l]);
  }

  k_gemm<<<dim3(1024 / 64, 16384 / 64), 256, 0, stream>>>(CAT, wf, out);
  (void)hipMemsetAsync(ST, 0, 2048 * sizeof(double), stream);
  k_fstats<<<dim3(64), 256, 0, stream>>>(out, ST);
  k_fnorm<<<dim3(16384 * 1024 / 256), 256, 0, stream>>>(out, ST, gf, bf);
}

// Round 12
// 4077.172 us; speedup vs baseline: 1.6292x; 1.6292x over previous
//
#include <hip/hip_runtime.h>

#define NPTS 2048
#define BATCH 8
#define KNN 20

// ---------------------------------------------------------------------------
// Model (R0-R11, VERIFIED PASSING): ref = np transcription, einsum->sgemm
// (per-element ascending FMA chains), sq = multiply-temp + numpy pairwise
// non-FMA sum, d = (2e - sqn) - sqm left-assoc f32, top-k desc ties->lower
// index, conv = single FMA chain over concatenated 2C h-vector, BN f32
// left-assoc with f64 stats. Selection ranks on our f32 D.

// ---------------------------------------------------------------------------
// sq, C==3: products rounded individually, sequential sum (numpy n<8).
__global__ void k_sqnorm3(const float* __restrict__ fin, int stride, int off,
                          float* __restrict__ sq) {
  int i = blockIdx.x * 256 + threadIdx.x;
  const float* r = fin + (size_t)i * stride + off;
  float p0 = __fmul_rn(r[0], r[0]);
  float p1 = __fmul_rn(r[1], r[1]);
  float p2 = __fmul_rn(r[2], r[2]);
  sq[i] = __fadd_rn(__fadd_rn(p0, p1), p2);
}

// sq, C=64/128 (<=128): numpy pairwise 8-accumulator pattern, non-FMA.
template <int C>
__global__ void k_sqnorm_pw(const float* __restrict__ fin, int stride, int off,
                            float* __restrict__ sq) {
  int i = blockIdx.x * 256 + threadIdx.x;
  const float* r = fin + (size_t)i * stride + off;
  float a8[8];
  #pragma unroll
  for (int j = 0; j < 8; ++j) a8[j] = __fmul_rn(r[j], r[j]);
  #pragma unroll
  for (int ii = 8; ii < C; ii += 8)
    #pragma unroll
    for (int j = 0; j < 8; ++j)
      a8[j] = __fadd_rn(a8[j], __fmul_rn(r[ii + j], r[ii + j]));
  sq[i] = __fadd_rn(__fadd_rn(__fadd_rn(a8[0], a8[1]), __fadd_rn(a8[2], a8[3])),
                    __fadd_rn(__fadd_rn(a8[4], a8[5]), __fadd_rn(a8[6], a8[7])));
}

// ---------------------------------------------------------------------------
// Screen GEMM (sgemm-emulating): per-element single fmaf chain ascending k;
// D = (2e - sqn) - sqm left-assoc. 2 batches per dispatch.
__global__ void __launch_bounds__(256) k_screen(const float* __restrict__ fin,
                                                int stride, int off, int KK,
                                                const float* __restrict__ sq,
                                                int bbase, float* __restrict__ Dbase) {
  __shared__ float As[16][68];
  __shared__ float Bs[16][68];
  int tid = threadIdx.x;
  int b = bbase + blockIdx.z;
  float* D = Dbase + (size_t)blockIdx.z * NPTS * NPTS;
  int n0 = blockIdx.y * 64, m0 = blockIdx.x * 64;
  const float* fb = fin + (size_t)b * NPTS * stride + off;
  int lr = tid >> 2;            // 0..63
  int lk = (tid & 3) * 4;       // 0,4,8,12
  float acc[4][4];
  #pragma unroll
  for (int i = 0; i < 4; ++i)
    #pragma unroll
    for (int j = 0; j < 4; ++j) acc[i][j] = 0.f;
  for (int k0 = 0; k0 < KK; k0 += 16) {
    float4 av, bv;
    const float* arow = fb + (size_t)(n0 + lr) * stride + k0 + lk;
    const float* brow = fb + (size_t)(m0 + lr) * stride + k0 + lk;
    int rem = KK - k0;
    if (lk + 4 <= rem) { av = *(const float4*)arow; bv = *(const float4*)brow; }
    else {
      av.x = (lk + 0 < rem) ? arow[0] : 0.f;  bv.x = (lk + 0 < rem) ? brow[0] : 0.f;
      av.y = (lk + 1 < rem) ? arow[1] : 0.f;  bv.y = (lk + 1 < rem) ? brow[1] : 0.f;
      av.z = (lk + 2 < rem) ? arow[2] : 0.f;  bv.z = (lk + 2 < rem) ? brow[2] : 0.f;
      av.w = (lk + 3 < rem) ? arow[3] : 0.f;  bv.w = (lk + 3 < rem) ? brow[3] : 0.f;
    }
    __syncthreads();
    As[lk+0][lr] = av.x; As[lk+1][lr] = av.y; As[lk+2][lr] = av.z; As[lk+3][lr] = av.w;
    Bs[lk+0][lr] = bv.x; Bs[lk+1][lr] = bv.y; Bs[lk+2][lr] = bv.z; Bs[lk+3][lr] = bv.w;
    __syncthreads();
    int ty = tid >> 4, tx = tid & 15;
    #pragma unroll
    for (int kk = 0; kk < 16; ++kk) {
      float4 a = *(const float4*)&As[kk][ty * 4];
      float4 b2 = *(const float4*)&Bs[kk][tx * 4];
      acc[0][0] = fmaf(a.x, b2.x, acc[0][0]); acc[0][1] = fmaf(a.x, b2.y, acc[0][1]);
      acc[0][2] = fmaf(a.x, b2.z, acc[0][2]); acc[0][3] = fmaf(a.x, b2.w, acc[0][3]);
      acc[1][0] = fmaf(a.y, b2.x, acc[1][0]); acc[1][1] = fmaf(a.y, b2.y, acc[1][1]);
      acc[1][2] = fmaf(a.y, b2.z, acc[1][2]); acc[1][3] = fmaf(a.y, b2.w, acc[1][3]);
      acc[2][0] = fmaf(a.z, b2.x, acc[2][0]); acc[2][1] = fmaf(a.z, b2.y, acc[2][1]);
      acc[2][2] = fmaf(a.z, b2.z, acc[2][2]); acc[2][3] = fmaf(a.z, b2.w, acc[2][3]);
      acc[3][0] = fmaf(a.w, b2.x, acc[3][0]); acc[3][1] = fmaf(a.w, b2.y, acc[3][1]);
      acc[3][2] = fmaf(a.w, b2.z, acc[3][2]); acc[3][3] = fmaf(a.w, b2.w, acc[3][3]);
    }
  }
  int ty = tid >> 4, tx = tid & 15;
  const float* sqb = sq + b * NPTS;
  #pragma unroll
  for (int i = 0; i < 4; ++i) {
    float sn = sqb[n0 + ty * 4 + i];
    #pragma unroll
    for (int j = 0; j < 4; ++j) {
      float d = __fsub_rn(__fsub_rn(__fmul_rn(2.f, acc[i][j]), sn), sqb[m0 + tx * 4 + j]);
      D[(size_t)(n0 + ty * 4 + i) * NPTS + m0 + tx * 4 + j] = d;
    }
  }
}

// ---------------------------------------------------------------------------
__device__ inline unsigned f2u(float f) {
  unsigned b = __float_as_uint(f);
  return b ^ (unsigned)(((int)b >> 31) | 0x80000000);
}

// top-20 on f32 D: desc, ties -> lower index.
__device__ inline void row_select(const float (&dv)[32], int wt,
                                  int*   __restrict__ candc,   // [256]
                                  float* __restrict__ candf,   // [256]
                                  int* __restrict__ outp) {
  unsigned u[32];
  #pragma unroll
  for (int s = 0; s < 32; ++s) u[s] = f2u(dv[s]);
  unsigned P = 0u;
  for (int k = 31; k >= 8; --k) {
    unsigned Pt = P | (1u << k);
    int bc = 0;
    #pragma unroll
    for (int s = 0; s < 32; ++s) bc += (u[s] >= Pt) ? 1 : 0;
    #pragma unroll
    for (int o = 1; o < 64; o <<= 1) bc += __shfl_xor(bc, o, 64);
    if (bc >= 32) P = Pt;
  }
  const unsigned T = P;
  int cnt = 0;
  #pragma unroll
  for (int s = 0; s < 32; ++s) {
    bool pred = (u[s] >= T);
    unsigned long long mk = __ballot(pred);
    if (pred) {
      int pos = cnt + (int)__popcll(mk & ((1ull << wt) - 1ull));
      if (pos < 256) {
        candc[pos] = ((s >> 2) << 8) + (wt << 2) + (s & 3);
        candf[pos] = dv[s];
      }
    }
    cnt += (int)__popcll(mk);
  }
  if (cnt > 256) cnt = 256;
  __threadfence_block();
  #pragma unroll
  for (int q = 0; q < 4; ++q) {
    int ci = wt + 64 * q;
    if (ci < cnt) {
      int   mq = candc[ci];
      float dq = candf[ci];
      int r = 0;
      for (int j = 0; j < cnt; ++j) {
        float dj = candf[j]; int mj = candc[j];
        r += (dj > dq || (dj == dq && mj < mq)) ? 1 : 0;
      }
      if (r < KNN) outp[r] = mq;
    }
  }
}

__global__ void __launch_bounds__(256) k_select(const float* __restrict__ Dbase,
                                                int bbase, int* __restrict__ idxo) {
  __shared__ int   candcS[4][256];
  __shared__ float candfS[4][256];
  int tid = threadIdx.x;
  int wave = tid >> 6, wt = tid & 63;
  int b = bbase + blockIdx.y;
  const float* D = Dbase + (size_t)blockIdx.y * NPTS * NPTS;
  int n = blockIdx.x * 4 + wave;
  float dv[32];
  const float4* rp = (const float4*)(D + (size_t)n * NPTS) + wt;
  #pragma unroll
  for (int j = 0; j < 8; ++j) {
    float4 v = rp[64 * j];
    dv[j*4+0] = v.x; dv[j*4+1] = v.y; dv[j*4+2] = v.z; dv[j*4+3] = v.w;
  }
  row_select(dv, wt, candcS[wave], candfS[wave],
             idxo + ((size_t)b * NPTS + n) * KNN);
}

// ---------------------------------------------------------------------------
// Edge-conv layer 0 (2C=6): verified small kernel, kept as-is.
template <int C, int F>
__global__ void __launch_bounds__(256) k_econv(const float* __restrict__ fin,
                                               int stride, int off,
                                               const int* __restrict__ idx,
                                               const float* __restrict__ w,
                                               const float* __restrict__ g,
                                               float* __restrict__ cat, int catoff,
                                               double* __restrict__ stats) {
  const int TC = 2 * C;
  __shared__ float hS[20][2 * C + 4];
  __shared__ float wS[32][2 * C + 4];
  __shared__ float xnS[C];
  int tid = threadIdx.x;
  int n = blockIdx.x;
  int f0 = blockIdx.y * 32;
  int gbase = n & ~(NPTS - 1);
  for (int c = tid; c < C; c += 256) xnS[c] = fin[(size_t)n * stride + off + c];
  __syncthreads();
  for (int i = tid; i < 20 * C; i += 256) {
    int k = i / C, c = i - k * C;
    int m = idx[n * KNN + k];
    float xm = fin[(size_t)(gbase + m) * stride + off + c];
    hS[k][c] = __fsub_rn(xm, xnS[c]);
    hS[k][C + c] = xnS[c];
  }
  for (int i = tid; i < 32 * TC; i += 256) {
    int fr = i / TC, c = i - fr * TC;
    wS[fr][c] = w[(size_t)(f0 + fr) * TC + c];
  }
  __syncthreads();
  int f = tid >> 3, kl = tid & 7;      // 32 f x 8 k-lanes
  float mx = -1e30f, mn = 1e30f;
  double s = 0.0, ss = 0.0;
  for (int k = kl; k < KNN; k += 8) {
    float y = 0.f;
    #pragma unroll 8
    for (int c = 0; c < TC; ++c)
      y = fmaf(hS[k][c], wS[f][c], y);
    mx = fmaxf(mx, y); mn = fminf(mn, y);
    double yd = (double)y;
    s += yd; ss = fma(yd, yd, ss);
  }
  #pragma unroll
  for (int o = 4; o > 0; o >>= 1) {
    mx = fmaxf(mx, __shfl_down(mx, o, 8));
    mn = fminf(mn, __shfl_down(mn, o, 8));
    s += __shfl_down(s, o, 8);
    ss += __shfl_down(ss, o, 8);
  }
  if (kl == 0) {
    float gg = g[f0 + f];
    cat[(size_t)n * 512 + catoff + f0 + f] = (gg >= 0.f) ? mx : mn;
    atomicAdd(&stats[f0 + f], s);
    atomicAdd(&stats[F + f0 + f], ss);
  }
}

// ---------------------------------------------------------------------------
// Edge-conv layers 1-3, GEMM-ified (bit-identical chains): (n,k) x 2C @ 2C x F
// as a 64-row (3 n x 20 k + 4 pad) x 64-f tile, 4x4 register blocking,
// ds_read_b128 operands. Per-output accumulation = single fmaf chain with c
// ascending (c0 outer, kk inner) == the verified per-(n,k,f) chain.
// In-block k-reduction via LDS y-tile (fmax exact-assoc; f64 stats).
template <int C, int F>
__global__ void __launch_bounds__(256) k_econv_g(const float* __restrict__ fin,
                                                 int stride, int off,
                                                 const int* __restrict__ idx,
                                                 const float* __restrict__ w,
                                                 const float* __restrict__ g,
                                                 float* __restrict__ cat, int catoff,
                                                 double* __restrict__ stats) {
  const int TC = 2 * C;
  __shared__ float hS[16][68];
  __shared__ float wS[16][68];
  __shared__ float yS[64][68];
  __shared__ float xnS[3 * C];
  __shared__ int   mS[64];
  int tid = threadIdx.x;
  int n0 = blockIdx.x * 3;           // 3 n's per block (rows = k*3+n)
  int f0 = blockIdx.y * 64;
  if (tid < 64) {
    int row = tid;
    int k = row / 3, n = row - 3 * k;
    int ng = n0 + n;
    mS[row] = (row < 60 && ng < BATCH * NPTS) ? idx[ng * KNN + k] : 0;
  }
  for (int i = tid; i < 3 * C; i += 256) {
    int n = i / C, c = i - n * C;
    int ng = n0 + n;
    xnS[i] = (ng < BATCH * NPTS) ? fin[(size_t)ng * stride + off + c] : 0.f;
  }
  __syncthreads();
  int ty = tid >> 4, tx = tid & 15;
  float acc[4][4];
  #pragma unroll
  for (int i = 0; i < 4; ++i)
    #pragma unroll
    for (int j = 0; j < 4; ++j) acc[i][j] = 0.f;
  for (int c0 = 0; c0 < TC; c0 += 16) {
    float hv[4], wv[4];
    #pragma unroll
    for (int q = 0; q < 4; ++q) {
      int i = tid + 256 * q;           // 0..1023
      int row = i >> 4, cc = i & 15;
      int c = c0 + cc;
      float v = 0.f;
      if (row < 60) {
        int k = row / 3, n = row - 3 * k;
        (void)k;
        int ng = n0 + n;
        int gb = ng & ~(NPTS - 1);
        if (c < C) {
          float xm = fin[(size_t)(gb + mS[row]) * stride + off + c];
          v = __fsub_rn(xm, xnS[n * C + c]);
        } else {
          v = xnS[n * C + c - C];
        }
      }
      hv[q] = v;
      int kk = i >> 6, f = i & 63;     // 16 x 64
      wv[q] = w[(size_t)(f0 + f) * TC + c0 + kk];
    }
    __syncthreads();
    #pragma unroll
    for (int q = 0; q < 4; ++q) {
      int i = tid + 256 * q;
      hS[i & 15][i >> 4] = hv[q];
      wS[i >> 6][i & 63] = wv[q];
    }
    __syncthreads();
    #pragma unroll
    for (int kk = 0; kk < 16; ++kk) {
      float4 a = *(const float4*)&hS[kk][ty * 4];
      float4 b = *(const float4*)&wS[kk][tx * 4];
      acc[0][0] = fmaf(a.x, b.x, acc[0][0]); acc[0][1] = fmaf(a.x, b.y, acc[0][1]);
      acc[0][2] = fmaf(a.x, b.z, acc[0][2]); acc[0][3] = fmaf(a.x, b.w, acc[0][3]);
      acc[1][0] = fmaf(a.y, b.x, acc[1][0]); acc[1][1] = fmaf(a.y, b.y, acc[1][1]);
      acc[1][2] = fmaf(a.y, b.z, acc[1][2]); acc[1][3] = fmaf(a.y, b.w, acc[1][3]);
      acc[2][0] = fmaf(a.z, b.x, acc[2][0]); acc[2][1] = fmaf(a.z, b.y, acc[2][1]);
      acc[2][2] = fmaf(a.z, b.z, acc[2][2]); acc[2][3] = fmaf(a.z, b.w, acc[2][3]);
      acc[3][0] = fmaf(a.w, b.x, acc[3][0]); acc[3][1] = fmaf(a.w, b.y, acc[3][1]);
      acc[3][2] = fmaf(a.w, b.z, acc[3][2]); acc[3][3] = fmaf(a.w, b.w, acc[3][3]);
    }
  }
  #pragma unroll
  for (int i = 0; i < 4; ++i)
    #pragma unroll
    for (int j = 0; j < 4; ++j)
      yS[ty * 4 + i][tx * 4 + j] = acc[i][j];
  __syncthreads();
  if (tid < 192) {
    int n = tid >> 6, f = tid & 63;
    int ng = n0 + n;
    if (ng < BATCH * NPTS) {
      float mx = -1e30f, mn = 1e30f;
      double s = 0.0, ss = 0.0;
      #pragma unroll
      for (int k = 0; k < KNN; ++k) {
        float y = yS[k * 3 + n][f];
        mx = fmaxf(mx, y); mn = fminf(mn, y);
        double yd = (double)y;
        s += yd; ss = fma(yd, yd, ss);
      }
      float gg = g[f0 + f];
      cat[(size_t)ng * 512 + catoff + f0 + f] = (gg >= 0.f) ? mx : mn;
      atomicAdd(&stats[f0 + f], s);
      atomicAdd(&stats[F + f0 + f], ss);
    }
  }
}

// BN + leaky on CAT slice: f64 stats, f32 left-assoc application.
__global__ void k_bn(float* __restrict__ cat, const double* __restrict__ stats,
                     const float* __restrict__ g, const float* __restrict__ bb,
                     int Fbits, int catoff) {
  int i = blockIdx.x * 256 + threadIdx.x;
  int F = 1 << Fbits;
  int f = i & (F - 1);
  int bn = i >> Fbits;
  const double invCnt = 1.0 / (double)(BATCH * NPTS * KNN);
  double mean64 = stats[f] * invCnt;
  double ex2 = stats[F + f] * invCnt;
  double var64 = ex2 - mean64 * mean64;
  if (var64 < 0.0) var64 = 0.0;
  float mean32 = (float)mean64;
  float vs = (float)var64;
  float rs = 1.0f / __fsqrt_rn(__fadd_rn(vs, 1e-5f));
  float* p = &cat[(size_t)bn * 512 + catoff + f];
  float y = *p;
  float u = __fmul_rn(g[f], __fsub_rn(y, mean32));
  float t = __fadd_rn(__fmul_rn(u, rs), bb[f]);
  *p = (t >= 0.f) ? t : __fmul_rn(0.2f, t);
}

// ---------------------------------------------------------------------------
// Final GEMM (values only): CAT @ wf^T -> out f32.
__global__ void __launch_bounds__(256) k_gemm(const float* __restrict__ A,
                                              const float* __restrict__ Bw,
                                              float* __restrict__ Cc) {
  __shared__ float As[16][68];
  __shared__ float Bs[16][68];
  int tid = threadIdx.x;
  int m0 = blockIdx.y * 64, f0 = blockIdx.x * 64;
  int ty = tid >> 4, tx = tid & 15;
  int lr = tid >> 2;
  int lk = (tid & 3) * 4;
  float acc[4][4];
  #pragma unroll
  for (int i = 0; i < 4; ++i)
    #pragma unroll
    for (int j = 0; j < 4; ++j) acc[i][j] = 0.f;
  for (int k0 = 0; k0 < 512; k0 += 16) {
    float4 av = *(const float4*)&A [(size_t)(m0 + lr) * 512 + k0 + lk];
    float4 bv = *(const float4*)&Bw[(size_t)(f0 + lr) * 512 + k0 + lk];
    __syncthreads();
    As[lk+0][lr] = av.x; As[lk+1][lr] = av.y; As[lk+2][lr] = av.z; As[lk+3][lr] = av.w;
    Bs[lk+0][lr] = bv.x; Bs[lk+1][lr] = bv.y; Bs[lk+2][lr] = bv.z; Bs[lk+3][lr] = bv.w;
    __syncthreads();
    #pragma unroll
    for (int kk = 0; kk < 16; ++kk) {
      float4 a = *(const float4*)&As[kk][ty * 4];
      float4 b = *(const float4*)&Bs[kk][tx * 4];
      acc[0][0] = fmaf(a.x, b.x, acc[0][0]); acc[0][1] = fmaf(a.x, b.y, acc[0][1]);
      acc[0][2] = fmaf(a.x, b.z, acc[0][2]); acc[0][3] = fmaf(a.x, b.w, acc[0][3]);
      acc[1][0] = fmaf(a.y, b.x, acc[1][0]); acc[1][1] = fmaf(a.y, b.y, acc[1][1]);
      acc[1][2] = fmaf(a.y, b.z, acc[1][2]); acc[1][3] = fmaf(a.y, b.w, acc[1][3]);
      acc[2][0] = fmaf(a.z, b.x, acc[2][0]); acc[2][1] = fmaf(a.z, b.y, acc[2][1]);
      acc[2][2] = fmaf(a.z, b.z, acc[2][2]); acc[2][3] = fmaf(a.z, b.w, acc[2][3]);
      acc[3][0] = fmaf(a.w, b.x, acc[3][0]); acc[3][1] = fmaf(a.w, b.y, acc[3][1]);
      acc[3][2] = fmaf(a.w, b.z, acc[3][2]); acc[3][3] = fmaf(a.w, b.w, acc[3][3]);
    }
  }
  #pragma unroll
  for (int i = 0; i < 4; ++i)
    #pragma unroll
    for (int j = 0; j < 4; ++j)
      Cc[(size_t)(m0 + ty * 4 + i) * 1024 + f0 + tx * 4 + j] = acc[i][j];
}

__global__ void k_fstats(const float* __restrict__ y, double* __restrict__ st) {
  int tid = threadIdx.x;
  int r0 = blockIdx.x * 256;
  double s[4] = {0,0,0,0}, ss[4] = {0,0,0,0};
  for (int r = r0; r < r0 + 256; ++r) {
    const float* row = y + (size_t)r * 1024;
    #pragma unroll
    for (int q = 0; q < 4; ++q) {
      double v = (double)row[tid + 256 * q];
      s[q] += v; ss[q] = fma(v, v, ss[q]);
    }
  }
  #pragma unroll
  for (int q = 0; q < 4; ++q) {
    atomicAdd(&st[tid + 256 * q], s[q]);
    atomicAdd(&st[1024 + tid + 256 * q], ss[q]);
  }
}

__global__ void k_fnorm(float* __restrict__ y, const double* __restrict__ st,
                        const float* __restrict__ g, const float* __restrict__ bb) {
  int i = blockIdx.x * 256 + threadIdx.x;
  int f = i & 1023;
  const double invCnt = 1.0 / 16384.0;
  double mean = st[f] * invCnt;
  double ex2  = st[1024 + f] * invCnt;
  double var  = ex2 - mean * mean;
  if (var < 0.0) var = 0.0;
  double rs   = rsqrt(var + 1e-5);
  float v = y[i];
  float t = (float)((double)g[f] * ((double)v - mean) * rs + (double)bb[f]);
  y[i] = (t >= 0.f) ? t : 0.2f * t;
}

// ---------------------------------------------------------------------------
extern "C" void kernel_launch(void* const* d_in, const int* in_sizes, int n_in,
                              void* d_out, int out_size, void* d_ws, size_t ws_size,
                              hipStream_t stream) {
  const float* x  = (const float*)d_in[0];
  const float* W[4]  = {(const float*)d_in[1], (const float*)d_in[4],
                        (const float*)d_in[7], (const float*)d_in[10]};
  const float* G[4]  = {(const float*)d_in[2], (const float*)d_in[5],
                        (const float*)d_in[8], (const float*)d_in[11]};
  const float* Bb[4] = {(const float*)d_in[3], (const float*)d_in[6],
                        (const float*)d_in[9], (const float*)d_in[12]};
  const float* wf = (const float*)d_in[13];
  const float* gf = (const float*)d_in[14];
  const float* bf = (const float*)d_in[15];
  float* out = (float*)d_out;

  // workspace: SQ, CAT, ZT (D scratch), ST (f64 stats), IDX.
  float* ws  = (float*)d_ws;
  float* SQ  = ws;                 // 16384 f
  float* CAT = SQ + 16384;         // 8,388,608 f
  float* ZT  = CAT + 8388608;      // 8,388,608 f (D scratch, 2 batches)
  double* ST = (double*)(ZT + 8388608);    // 2048 d
  int*   IDX = (int*)(ST + 2048);  // 16384*20 ints

  const int Cs[4]      = {3, 64, 64, 128};
  const int Fs[4]      = {64, 64, 128, 256};
  const int Fbits[4]   = {6, 6, 7, 8};
  const int offs[4]    = {0, 0, 64, 128};
  const int strides[4] = {3, 512, 512, 512};
  const int catoffs[4] = {0, 64, 128, 256};
  const int NB3 = (BATCH * NPTS + 2) / 3;  // 5462 blocks of 3 n's

  for (int l = 0; l < 4; ++l) {
    const float* fin = (l == 0) ? x : CAT;
    int C = Cs[l], F = Fs[l];
    switch (C) {
      case 3:   k_sqnorm3<<<dim3(64), 256, 0, stream>>>(fin, strides[l], offs[l], SQ); break;
      case 64:  k_sqnorm_pw<64><<<dim3(64), 256, 0, stream>>>(fin, strides[l], offs[l], SQ); break;
      default:  k_sqnorm_pw<128><<<dim3(64), 256, 0, stream>>>(fin, strides[l], offs[l], SQ); break;
    }
    for (int bb = 0; bb < BATCH; bb += 2) {
      k_screen<<<dim3(NPTS / 64, NPTS / 64, 2), 256, 0, stream>>>(fin, strides[l], offs[l], C, SQ, bb, ZT);
      k_select<<<dim3(NPTS / 4, 2), 256, 0, stream>>>(ZT, bb, IDX);
    }
    (void)hipMemsetAsync(ST, 0, 2 * F * sizeof(double), stream);
    switch (l) {
      case 0: k_econv<3, 64>     <<<dim3(16384, 2), 256, 0, stream>>>(fin, strides[l], offs[l], IDX, W[l], G[l], CAT, catoffs[l], ST); break;
      case 1: k_econv_g<64, 64>  <<<dim3(NB3, 1), 256, 0, stream>>>(fin, strides[l], offs[l], IDX, W[l], G[l], CAT, catoffs[l], ST); break;
      case 2: k_econv_g<64, 128> <<<dim3(NB3, 2), 256, 0, stream>>>(fin, strides[l], offs[l], IDX, W[l], G[l], CAT, catoffs[l], ST); break;
      default: k_econv_g<128, 256><<<dim3(NB3, 4), 256, 0, stream>>>(fin, strides[l], offs[l], IDX, W[l], G[l], CAT, catoffs[l], ST); break;
    }
    k_bn<<<dim3(BATCH * NPTS * F / 256), 256, 0, stream>>>(CAT, ST, G[l], Bb[l], Fbits[l], catoffs[l]);
  }

  k_gemm<<<dim3(1024 / 64, 16384 / 64), 256, 0, stream>>>(CAT, wf, out);
  (void)hipMemsetAsync(ST, 0, 2048 * sizeof(double), stream);
  k_fstats<<<dim3(64), 256, 0, stream>>>(out, ST);
  k_fnorm<<<dim3(16384 * 1024 / 256), 256, 0, stream>>>(out, ST, gf, bf);
}

// Round 14
// 3285.954 us; speedup vs baseline: 2.0215x; 1.2408x over previous
//
#include <hip/hip_runtime.h>

#define NPTS 2048
#define BATCH 8
#define KNN 20

// ---------------------------------------------------------------------------
// Model (R0-R12, VERIFIED PASSING): ref = np transcription, einsum->sgemm
// (per-element ascending FMA chains), sq = multiply-temp + numpy pairwise
// non-FMA sum, d = (2e - sqn) - sqm left-assoc f32, top-k desc ties->lower
// index, conv = single FMA chain over concatenated 2C h-vector, BN f32
// left-assoc with f64 stats. Selection ranks on our f32 D.

// ---------------------------------------------------------------------------
// sq, C==3: products rounded individually, sequential sum (numpy n<8).
__global__ void k_sqnorm3(const float* __restrict__ fin, int stride, int off,
                          float* __restrict__ sq) {
  int i = blockIdx.x * 256 + threadIdx.x;
  const float* r = fin + (size_t)i * stride + off;
  float p0 = __fmul_rn(r[0], r[0]);
  float p1 = __fmul_rn(r[1], r[1]);
  float p2 = __fmul_rn(r[2], r[2]);
  sq[i] = __fadd_rn(__fadd_rn(p0, p1), p2);
}

// sq, C=64/128 (<=128): numpy pairwise 8-accumulator pattern, non-FMA.
template <int C>
__global__ void k_sqnorm_pw(const float* __restrict__ fin, int stride, int off,
                            float* __restrict__ sq) {
  int i = blockIdx.x * 256 + threadIdx.x;
  const float* r = fin + (size_t)i * stride + off;
  float a8[8];
  #pragma unroll
  for (int j = 0; j < 8; ++j) a8[j] = __fmul_rn(r[j], r[j]);
  #pragma unroll
  for (int ii = 8; ii < C; ii += 8)
    #pragma unroll
    for (int j = 0; j < 8; ++j)
      a8[j] = __fadd_rn(a8[j], __fmul_rn(r[ii + j], r[ii + j]));
  sq[i] = __fadd_rn(__fadd_rn(__fadd_rn(a8[0], a8[1]), __fadd_rn(a8[2], a8[3])),
                    __fadd_rn(__fadd_rn(a8[4], a8[5]), __fadd_rn(a8[6], a8[7])));
}

// ---------------------------------------------------------------------------
// Screen GEMM (sgemm-emulating): per-element single fmaf chain ascending k;
// D = (2e - sqn) - sqm left-assoc. 2 batches per dispatch.
__global__ void __launch_bounds__(256) k_screen(const float* __restrict__ fin,
                                                int stride, int off, int KK,
                                                const float* __restrict__ sq,
                                                int bbase, float* __restrict__ Dbase) {
  __shared__ float As[16][68];
  __shared__ float Bs[16][68];
  int tid = threadIdx.x;
  int b = bbase + blockIdx.z;
  float* D = Dbase + (size_t)blockIdx.z * NPTS * NPTS;
  int n0 = blockIdx.y * 64, m0 = blockIdx.x * 64;
  const float* fb = fin + (size_t)b * NPTS * stride + off;
  int lr = tid >> 2;            // 0..63
  int lk = (tid & 3) * 4;       // 0,4,8,12
  float acc[4][4];
  #pragma unroll
  for (int i = 0; i < 4; ++i)
    #pragma unroll
    for (int j = 0; j < 4; ++j) acc[i][j] = 0.f;
  for (int k0 = 0; k0 < KK; k0 += 16) {
    float4 av, bv;
    const float* arow = fb + (size_t)(n0 + lr) * stride + k0 + lk;
    const float* brow = fb + (size_t)(m0 + lr) * stride + k0 + lk;
    int rem = KK - k0;
    if (lk + 4 <= rem) { av = *(const float4*)arow; bv = *(const float4*)brow; }
    else {
      av.x = (lk + 0 < rem) ? arow[0] : 0.f;  bv.x = (lk + 0 < rem) ? brow[0] : 0.f;
      av.y = (lk + 1 < rem) ? arow[1] : 0.f;  bv.y = (lk + 1 < rem) ? brow[1] : 0.f;
      av.z = (lk + 2 < rem) ? arow[2] : 0.f;  bv.z = (lk + 2 < rem) ? brow[2] : 0.f;
      av.w = (lk + 3 < rem) ? arow[3] : 0.f;  bv.w = (lk + 3 < rem) ? brow[3] : 0.f;
    }
    __syncthreads();
    As[lk+0][lr] = av.x; As[lk+1][lr] = av.y; As[lk+2][lr] = av.z; As[lk+3][lr] = av.w;
    Bs[lk+0][lr] = bv.x; Bs[lk+1][lr] = bv.y; Bs[lk+2][lr] = bv.z; Bs[lk+3][lr] = bv.w;
    __syncthreads();
    int ty = tid >> 4, tx = tid & 15;
    #pragma unroll
    for (int kk = 0; kk < 16; ++kk) {
      float4 a = *(const float4*)&As[kk][ty * 4];
      float4 b2 = *(const float4*)&Bs[kk][tx * 4];
      acc[0][0] = fmaf(a.x, b2.x, acc[0][0]); acc[0][1] = fmaf(a.x, b2.y, acc[0][1]);
      acc[0][2] = fmaf(a.x, b2.z, acc[0][2]); acc[0][3] = fmaf(a.x, b2.w, acc[0][3]);
      acc[1][0] = fmaf(a.y, b2.x, acc[1][0]); acc[1][1] = fmaf(a.y, b2.y, acc[1][1]);
      acc[1][2] = fmaf(a.y, b2.z, acc[1][2]); acc[1][3] = fmaf(a.y, b2.w, acc[1][3]);
      acc[2][0] = fmaf(a.z, b2.x, acc[2][0]); acc[2][1] = fmaf(a.z, b2.y, acc[2][1]);
      acc[2][2] = fmaf(a.z, b2.z, acc[2][2]); acc[2][3] = fmaf(a.z, b2.w, acc[2][3]);
      acc[3][0] = fmaf(a.w, b2.x, acc[3][0]); acc[3][1] = fmaf(a.w, b2.y, acc[3][1]);
      acc[3][2] = fmaf(a.w, b2.z, acc[3][2]); acc[3][3] = fmaf(a.w, b2.w, acc[3][3]);
    }
  }
  int ty = tid >> 4, tx = tid & 15;
  const float* sqb = sq + b * NPTS;
  #pragma unroll
  for (int i = 0; i < 4; ++i) {
    float sn = sqb[n0 + ty * 4 + i];
    #pragma unroll
    for (int j = 0; j < 4; ++j) {
      float d = __fsub_rn(__fsub_rn(__fmul_rn(2.f, acc[i][j]), sn), sqb[m0 + tx * 4 + j]);
      D[(size_t)(n0 + ty * 4 + i) * NPTS + m0 + tx * 4 + j] = d;
    }
  }
}

// ---------------------------------------------------------------------------
__device__ inline unsigned f2u(float f) {
  unsigned b = __float_as_uint(f);
  return b ^ (unsigned)(((int)b >> 31) | 0x80000000);
}

// top-20 on f32 D: desc, ties -> lower index.
__device__ inline void row_select(const float (&dv)[32], int wt,
                                  int*   __restrict__ candc,   // [256]
                                  float* __restrict__ candf,   // [256]
                                  int* __restrict__ outp) {
  unsigned u[32];
  #pragma unroll
  for (int s = 0; s < 32; ++s) u[s] = f2u(dv[s]);
  unsigned P = 0u;
  for (int k = 31; k >= 8; --k) {
    unsigned Pt = P | (1u << k);
    int bc = 0;
    #pragma unroll
    for (int s = 0; s < 32; ++s) bc += (u[s] >= Pt) ? 1 : 0;
    #pragma unroll
    for (int o = 1; o < 64; o <<= 1) bc += __shfl_xor(bc, o, 64);
    if (bc >= 32) P = Pt;
  }
  const unsigned T = P;
  int cnt = 0;
  #pragma unroll
  for (int s = 0; s < 32; ++s) {
    bool pred = (u[s] >= T);
    unsigned long long mk = __ballot(pred);
    if (pred) {
      int pos = cnt + (int)__popcll(mk & ((1ull << wt) - 1ull));
      if (pos < 256) {
        candc[pos] = ((s >> 2) << 8) + (wt << 2) + (s & 3);
        candf[pos] = dv[s];
      }
    }
    cnt += (int)__popcll(mk);
  }
  if (cnt > 256) cnt = 256;
  __threadfence_block();
  #pragma unroll
  for (int q = 0; q < 4; ++q) {
    int ci = wt + 64 * q;
    if (ci < cnt) {
      int   mq = candc[ci];
      float dq = candf[ci];
      int r = 0;
      for (int j = 0; j < cnt; ++j) {
        float dj = candf[j]; int mj = candc[j];
        r += (dj > dq || (dj == dq && mj < mq)) ? 1 : 0;
      }
      if (r < KNN) outp[r] = mq;
    }
  }
}

__global__ void __launch_bounds__(256) k_select(const float* __restrict__ Dbase,
                                                int bbase, int* __restrict__ idxo) {
  __shared__ int   candcS[4][256];
  __shared__ float candfS[4][256];
  int tid = threadIdx.x;
  int wave = tid >> 6, wt = tid & 63;
  int b = bbase + blockIdx.y;
  const float* D = Dbase + (size_t)blockIdx.y * NPTS * NPTS;
  int n = blockIdx.x * 4 + wave;
  float dv[32];
  const float4* rp = (const float4*)(D + (size_t)n * NPTS) + wt;
  #pragma unroll
  for (int j = 0; j < 8; ++j) {
    float4 v = rp[64 * j];
    dv[j*4+0] = v.x; dv[j*4+1] = v.y; dv[j*4+2] = v.z; dv[j*4+3] = v.w;
  }
  row_select(dv, wt, candcS[wave], candfS[wave],
             idxo + ((size_t)b * NPTS + n) * KNN);
}

// ---------------------------------------------------------------------------
// Edge-conv layer 0 (2C=6): verified small kernel, kept as-is.
template <int C, int F>
__global__ void __launch_bounds__(256) k_econv(const float* __restrict__ fin,
                                               int stride, int off,
                                               const int* __restrict__ idx,
                                               const float* __restrict__ w,
                                               const float* __restrict__ g,
                                               float* __restrict__ cat, int catoff,
                                               double* __restrict__ stats) {
  const int TC = 2 * C;
  __shared__ float hS[20][2 * C + 4];
  __shared__ float wS[32][2 * C + 4];
  __shared__ float xnS[C];
  int tid = threadIdx.x;
  int n = blockIdx.x;
  int f0 = blockIdx.y * 32;
  int gbase = n & ~(NPTS - 1);
  for (int c = tid; c < C; c += 256) xnS[c] = fin[(size_t)n * stride + off + c];
  __syncthreads();
  for (int i = tid; i < 20 * C; i += 256) {
    int k = i / C, c = i - k * C;
    int m = idx[n * KNN + k];
    float xm = fin[(size_t)(gbase + m) * stride + off + c];
    hS[k][c] = __fsub_rn(xm, xnS[c]);
    hS[k][C + c] = xnS[c];
  }
  for (int i = tid; i < 32 * TC; i += 256) {
    int fr = i / TC, c = i - fr * TC;
    wS[fr][c] = w[(size_t)(f0 + fr) * TC + c];
  }
  __syncthreads();
  int f = tid >> 3, kl = tid & 7;      // 32 f x 8 k-lanes
  float mx = -1e30f, mn = 1e30f;
  double s = 0.0, ss = 0.0;
  for (int k = kl; k < KNN; k += 8) {
    float y = 0.f;
    #pragma unroll 8
    for (int c = 0; c < TC; ++c)
      y = fmaf(hS[k][c], wS[f][c], y);
    mx = fmaxf(mx, y); mn = fminf(mn, y);
    double yd = (double)y;
    s += yd; ss = fma(yd, yd, ss);
  }
  #pragma unroll
  for (int o = 4; o > 0; o >>= 1) {
    mx = fmaxf(mx, __shfl_down(mx, o, 8));
    mn = fminf(mn, __shfl_down(mn, o, 8));
    s += __shfl_down(s, o, 8);
    ss += __shfl_down(ss, o, 8);
  }
  if (kl == 0) {
    float gg = g[f0 + f];
    cat[(size_t)n * 512 + catoff + f0 + f] = (gg >= 0.f) ? mx : mn;
    atomicAdd(&stats[f0 + f], s);
    atomicAdd(&stats[F + f0 + f], ss);
  }
}

// ---------------------------------------------------------------------------
// w transpose: WT[c*F + f] = w[f*TC + c] (coalesced econv w loads).
__global__ void k_wt(const float* __restrict__ w, float* __restrict__ wt,
                     int TC, int F) {
  int i = blockIdx.x * 256 + threadIdx.x;
  if (i >= TC * F) return;
  int c = i / F, f = i - c * F;
  wt[i] = w[(size_t)f * TC + c];
}

// ---------------------------------------------------------------------------
// Edge-conv layers 1-3, GEMM-ified + f-block fused (bit-identical chains):
// (n,k) x 2C @ 2C x F as 64-row (3n x 20k interleaved + 4 pad) x (NFB x 64f)
// tiles, 4x4 register blocking per f-block, h gathered ONCE per n-block.
// Per-output chain: c0 outer, kk inner, ascending == verified semantics.
// k-reduction via LDS y-tile per f-block (fmax exact-assoc; f64 stats).
template <int C, int F, int NFB>
__global__ void __launch_bounds__(256) k_econv_g(const float* __restrict__ fin,
                                                 int stride, int off,
                                                 const int* __restrict__ idx,
                                                 const float* __restrict__ wt,  // [TC][F]
                                                 const float* __restrict__ g,
                                                 float* __restrict__ cat, int catoff,
                                                 double* __restrict__ stats) {
  const int TC = 2 * C;
  __shared__ float hS[16][68];
  __shared__ float wS[NFB][16][68];
  __shared__ float yS[64][68];
  __shared__ float xnS[3 * C];
  __shared__ int   mS[64];
  int tid = threadIdx.x;
  int n0 = blockIdx.x * 3;           // 3 n's per block (rows = k*3+n)
  if (tid < 64) {
    int row = tid;
    int k = row / 3, n = row - 3 * k;
    int ng = n0 + n;
    mS[row] = (row < 60 && ng < BATCH * NPTS) ? idx[ng * KNN + k] : 0;
  }
  for (int i = tid; i < 3 * C; i += 256) {
    int n = i / C, c = i - n * C;
    int ng = n0 + n;
    xnS[i] = (ng < BATCH * NPTS) ? fin[(size_t)ng * stride + off + c] : 0.f;
  }
  __syncthreads();
  int ty = tid >> 4, tx = tid & 15;
  float acc[NFB][4][4];
  #pragma unroll
  for (int fb = 0; fb < NFB; ++fb)
    #pragma unroll
    for (int i = 0; i < 4; ++i)
      #pragma unroll
      for (int j = 0; j < 4; ++j) acc[fb][i][j] = 0.f;
  for (int c0 = 0; c0 < TC; c0 += 16) {
    float hv[4], wv[NFB][4];
    #pragma unroll
    for (int q = 0; q < 4; ++q) {
      int i = tid + 256 * q;           // 0..1023
      int row = i >> 4, cc = i & 15;
      int c = c0 + cc;
      float v = 0.f;
      if (row < 60) {
        int k = row / 3, n = row - 3 * k;
        (void)k;
        int ng = n0 + n;
        int gb = ng & ~(NPTS - 1);
        if (c < C) {
          float xm = fin[(size_t)(gb + mS[row]) * stride + off + c];
          v = __fsub_rn(xm, xnS[n * C + c]);
        } else {
          v = xnS[n * C + c - C];
        }
      }
      hv[q] = v;
      int kk = i >> 6, f = i & 63;     // 16 x 64
      #pragma unroll
      for (int fb = 0; fb < NFB; ++fb)
        wv[fb][q] = wt[(size_t)(c0 + kk) * F + fb * 64 + f];
    }
    __syncthreads();
    #pragma unroll
    for (int q = 0; q < 4; ++q) {
      int i = tid + 256 * q;
      hS[i & 15][i >> 4] = hv[q];
      #pragma unroll
      for (int fb = 0; fb < NFB; ++fb)
        wS[fb][i >> 6][i & 63] = wv[fb][q];
    }
    __syncthreads();
    #pragma unroll
    for (int kk = 0; kk < 16; ++kk) {
      float4 a = *(const float4*)&hS[kk][ty * 4];
      #pragma unroll
      for (int fb = 0; fb < NFB; ++fb) {
        float4 b = *(const float4*)&wS[fb][kk][tx * 4];
        acc[fb][0][0] = fmaf(a.x, b.x, acc[fb][0][0]); acc[fb][0][1] = fmaf(a.x, b.y, acc[fb][0][1]);
        acc[fb][0][2] = fmaf(a.x, b.z, acc[fb][0][2]); acc[fb][0][3] = fmaf(a.x, b.w, acc[fb][0][3]);
        acc[fb][1][0] = fmaf(a.y, b.x, acc[fb][1][0]); acc[fb][1][1] = fmaf(a.y, b.y, acc[fb][1][1]);
        acc[fb][1][2] = fmaf(a.y, b.z, acc[fb][1][2]); acc[fb][1][3] = fmaf(a.y, b.w, acc[fb][1][3]);
        acc[fb][2][0] = fmaf(a.z, b.x, acc[fb][2][0]); acc[fb][2][1] = fmaf(a.z, b.y, acc[fb][2][1]);
        acc[fb][2][2] = fmaf(a.z, b.z, acc[fb][2][2]); acc[fb][2][3] = fmaf(a.z, b.w, acc[fb][2][3]);
        acc[fb][3][0] = fmaf(a.w, b.x, acc[fb][3][0]); acc[fb][3][1] = fmaf(a.w, b.y, acc[fb][3][1]);
        acc[fb][3][2] = fmaf(a.w, b.z, acc[fb][3][2]); acc[fb][3][3] = fmaf(a.w, b.w, acc[fb][3][3]);
      }
    }
  }
  #pragma unroll
  for (int fb = 0; fb < NFB; ++fb) {
    __syncthreads();
    #pragma unroll
    for (int i = 0; i < 4; ++i)
      #pragma unroll
      for (int j = 0; j < 4; ++j)
        yS[ty * 4 + i][tx * 4 + j] = acc[fb][i][j];
    __syncthreads();
    if (tid < 192) {
      int n = tid >> 6, f = tid & 63;
      int ng = n0 + n;
      if (ng < BATCH * NPTS) {
        float mx = -1e30f, mn = 1e30f;
        double s = 0.0, ss = 0.0;
        #pragma unroll
        for (int k = 0; k < KNN; ++k) {
          float y = yS[k * 3 + n][f];
          mx = fmaxf(mx, y); mn = fminf(mn, y);
          double yd = (double)y;
          s += yd; ss = fma(yd, yd, ss);
        }
        int fg = fb * 64 + f;
        float gg = g[fg];
        cat[(size_t)ng * 512 + catoff + fg] = (gg >= 0.f) ? mx : mn;
        atomicAdd(&stats[fg], s);
        atomicAdd(&stats[F + fg], ss);
      }
    }
  }
}

// BN + leaky on CAT slice: f64 stats, f32 left-assoc application.
__global__ void k_bn(float* __restrict__ cat, const double* __restrict__ stats,
                     const float* __restrict__ g, const float* __restrict__ bb,
                     int Fbits, int catoff) {
  int i = blockIdx.x * 256 + threadIdx.x;
  int F = 1 << Fbits;
  int f = i & (F - 1);
  int bn = i >> Fbits;
  const double invCnt = 1.0 / (double)(BATCH * NPTS * KNN);
  double mean64 = stats[f] * invCnt;
  double ex2 = stats[F + f] * invCnt;
  double var64 = ex2 - mean64 * mean64;
  if (var64 < 0.0) var64 = 0.0;
  float mean32 = (float)mean64;
  float vs = (float)var64;
  float rs = 1.0f / __fsqrt_rn(__fadd_rn(vs, 1e-5f));
  float* p = &cat[(size_t)bn * 512 + catoff + f];
  float y = *p;
  float u = __fmul_rn(g[f], __fsub_rn(y, mean32));
  float t = __fadd_rn(__fmul_rn(u, rs), bb[f]);
  *p = (t >= 0.f) ? t : __fmul_rn(0.2f, t);
}

// ---------------------------------------------------------------------------
// Final GEMM (values only): CAT @ wf^T -> out f32.
__global__ void __launch_bounds__(256) k_gemm(const float* __restrict__ A,
                                              const float* __restrict__ Bw,
                                              float* __restrict__ Cc) {
  __shared__ float As[16][68];
  __shared__ float Bs[16][68];
  int tid = threadIdx.x;
  int m0 = blockIdx.y * 64, f0 = blockIdx.x * 64;
  int ty = tid >> 4, tx = tid & 15;
  int lr = tid >> 2;
  int lk = (tid & 3) * 4;
  float acc[4][4];
  #pragma unroll
  for (int i = 0; i < 4; ++i)
    #pragma unroll
    for (int j = 0; j < 4; ++j) acc[i][j] = 0.f;
  for (int k0 = 0; k0 < 512; k0 += 16) {
    float4 av = *(const float4*)&A [(size_t)(m0 + lr) * 512 + k0 + lk];
    float4 bv = *(const float4*)&Bw[(size_t)(f0 + lr) * 512 + k0 + lk];
    __syncthreads();
    As[lk+0][lr] = av.x; As[lk+1][lr] = av.y; As[lk+2][lr] = av.z; As[lk+3][lr] = av.w;
    Bs[lk+0][lr] = bv.x; Bs[lk+1][lr] = bv.y; Bs[lk+2][lr] = bv.z; Bs[lk+3][lr] = bv.w;
    __syncthreads();
    #pragma unroll
    for (int kk = 0; kk < 16; ++kk) {
      float4 a = *(const float4*)&As[kk][ty * 4];
      float4 b = *(const float4*)&Bs[kk][tx * 4];
      acc[0][0] = fmaf(a.x, b.x, acc[0][0]); acc[0][1] = fmaf(a.x, b.y, acc[0][1]);
      acc[0][2] = fmaf(a.x, b.z, acc[0][2]); acc[0][3] = fmaf(a.x, b.w, acc[0][3]);
      acc[1][0] = fmaf(a.y, b.x, acc[1][0]); acc[1][1] = fmaf(a.y, b.y, acc[1][1]);
      acc[1][2] = fmaf(a.y, b.z, acc[1][2]); acc[1][3] = fmaf(a.y, b.w, acc[1][3]);
      acc[2][0] = fmaf(a.z, b.x, acc[2][0]); acc[2][1] = fmaf(a.z, b.y, acc[2][1]);
      acc[2][2] = fmaf(a.z, b.z, acc[2][2]); acc[2][3] = fmaf(a.z, b.w, acc[2][3]);
      acc[3][0] = fmaf(a.w, b.x, acc[3][0]); acc[3][1] = fmaf(a.w, b.y, acc[3][1]);
      acc[3][2] = fmaf(a.w, b.z, acc[3][2]); acc[3][3] = fmaf(a.w, b.w, acc[3][3]);
    }
  }
  #pragma unroll
  for (int i = 0; i < 4; ++i)
    #pragma unroll
    for (int j = 0; j < 4; ++j)
      Cc[(size_t)(m0 + ty * 4 + i) * 1024 + f0 + tx * 4 + j] = acc[i][j];
}

__global__ void k_fstats(const float* __restrict__ y, double* __restrict__ st) {
  int tid = threadIdx.x;
  int r0 = blockIdx.x * 256;
  double s[4] = {0,0,0,0}, ss[4] = {0,0,0,0};
  for (int r = r0; r < r0 + 256; ++r) {
    const float* row = y + (size_t)r * 1024;
    #pragma unroll
    for (int q = 0; q < 4; ++q) {
      double v = (double)row[tid + 256 * q];
      s[q] += v; ss[q] = fma(v, v, ss[q]);
    }
  }
  #pragma unroll
  for (int q = 0; q < 4; ++q) {
    atomicAdd(&st[tid + 256 * q], s[q]);
    atomicAdd(&st[1024 + tid + 256 * q], ss[q]);
  }
}

__global__ void k_fnorm(float* __restrict__ y, const double* __restrict__ st,
                        const float* __restrict__ g, const float* __restrict__ bb) {
  int i = blockIdx.x * 256 + threadIdx.x;
  int f = i & 1023;
  const double invCnt = 1.0 / 16384.0;
  double mean = st[f] * invCnt;
  double ex2  = st[1024 + f] * invCnt;
  double var  = ex2 - mean * mean;
  if (var < 0.0) var = 0.0;
  double rs   = rsqrt(var + 1e-5);
  float v = y[i];
  float t = (float)((double)g[f] * ((double)v - mean) * rs + (double)bb[f]);
  y[i] = (t >= 0.f) ? t : 0.2f * t;
}

// ---------------------------------------------------------------------------
extern "C" void kernel_launch(void* const* d_in, const int* in_sizes, int n_in,
                              void* d_out, int out_size, void* d_ws, size_t ws_size,
                              hipStream_t stream) {
  const float* x  = (const float*)d_in[0];
  const float* W[4]  = {(const float*)d_in[1], (const float*)d_in[4],
                        (const float*)d_in[7], (const float*)d_in[10]};
  const float* G[4]  = {(const float*)d_in[2], (const float*)d_in[5],
                        (const float*)d_in[8], (const float*)d_in[11]};
  const float* Bb[4] = {(const float*)d_in[3], (const float*)d_in[6],
                        (const float*)d_in[9], (const float*)d_in[12]};
  const float* wf = (const float*)d_in[13];
  const float* gf = (const float*)d_in[14];
  const float* bf = (const float*)d_in[15];
  float* out = (float*)d_out;

  // workspace: SQ, CAT, ZT (D scratch), ST (f64 stats), IDX, WT.
  float* ws  = (float*)d_ws;
  float* SQ  = ws;                 // 16384 f
  float* CAT = SQ + 16384;         // 8,388,608 f
  float* ZT  = CAT + 8388608;      // 8,388,608 f (D scratch, 2 batches)
  double* ST = (double*)(ZT + 8388608);    // 2048 d
  int*   IDX = (int*)(ST + 2048);  // 16384*20 ints
  float* WT  = (float*)(IDX + 16384 * KNN);  // 65,536 f (transposed w)

  const int Cs[4]      = {3, 64, 64, 128};
  const int Fs[4]      = {64, 64, 128, 256};
  const int Fbits[4]   = {6, 6, 7, 8};
  const int offs[4]    = {0, 0, 64, 128};
  const int strides[4] = {3, 512, 512, 512};
  const int catoffs[4] = {0, 64, 128, 256};
  const int NB3 = (BATCH * NPTS + 2) / 3;  // 5462 blocks of 3 n's

  for (int l = 0; l < 4; ++l) {
    const float* fin = (l == 0) ? x : CAT;
    int C = Cs[l], F = Fs[l];
    switch (C) {
      case 3:   k_sqnorm3<<<dim3(64), 256, 0, stream>>>(fin, strides[l], offs[l], SQ); break;
      case 64:  k_sqnorm_pw<64><<<dim3(64), 256, 0, stream>>>(fin, strides[l], offs[l], SQ); break;
      default:  k_sqnorm_pw<128><<<dim3(64), 256, 0, stream>>>(fin, strides[l], offs[l], SQ); break;
    }
    for (int bb = 0; bb < BATCH; bb += 2) {
      k_screen<<<dim3(NPTS / 64, NPTS / 64, 2), 256, 0, stream>>>(fin, strides[l], offs[l], C, SQ, bb, ZT);
      k_select<<<dim3(NPTS / 4, 2), 256, 0, stream>>>(ZT, bb, IDX);
    }
    (void)hipMemsetAsync(ST, 0, 2 * F * sizeof(double), stream);
    if (l > 0)
      k_wt<<<dim3((2 * C * F + 255) / 256), 256, 0, stream>>>(W[l], WT, 2 * C, F);
    switch (l) {
      case 0: k_econv<3, 64>        <<<dim3(16384, 2), 256, 0, stream>>>(fin, strides[l], offs[l], IDX, W[l], G[l], CAT, catoffs[l], ST); break;
      case 1: k_econv_g<64, 64, 1>  <<<dim3(NB3), 256, 0, stream>>>(fin, strides[l], offs[l], IDX, WT, G[l], CAT, catoffs[l], ST); break;
      case 2: k_econv_g<64, 128, 2> <<<dim3(NB3), 256, 0, stream>>>(fin, strides[l], offs[l], IDX, WT, G[l], CAT, catoffs[l], ST); break;
      default: k_econv_g<128, 256, 4><<<dim3(NB3), 256, 0, stream>>>(fin, strides[l], offs[l], IDX, WT, G[l], CAT, catoffs[l], ST); break;
    }
    k_bn<<<dim3(BATCH * NPTS * F / 256), 256, 0, stream>>>(CAT, ST, G[l], Bb[l], Fbits[l], catoffs[l]);
  }

  k_gemm<<<dim3(1024 / 64, 16384 / 64), 256, 0, stream>>>(CAT, wf, out);
  (void)hipMemsetAsync(ST, 0, 2048 * sizeof(double), stream);
  k_fstats<<<dim3(64), 256, 0, stream>>>(out, ST);
  k_fnorm<<<dim3(16384 * 1024 / 256), 256, 0, stream>>>(out, ST, gf, bf);
}

// Round 15
// 3276.978 us; speedup vs baseline: 2.0270x; 1.0027x over previous
//
#include <hip/hip_runtime.h>

#define NPTS 2048
#define BATCH 8
#define KNN 20

// ---------------------------------------------------------------------------
// Model (R0-R12, VERIFIED PASSING): ref = np transcription, einsum->sgemm
// (per-element ascending FMA chains), sq = multiply-temp + numpy pairwise
// non-FMA sum, d = (2e - sqn) - sqm left-assoc f32, top-k desc ties->lower
// index, conv = single FMA chain over concatenated 2C h-vector, BN f32
// left-assoc with f64 stats. Selection ranks on our f32 D.

// ---------------------------------------------------------------------------
// sq, C==3: products rounded individually, sequential sum (numpy n<8).
__global__ void k_sqnorm3(const float* __restrict__ fin, int stride, int off,
                          float* __restrict__ sq) {
  int i = blockIdx.x * 256 + threadIdx.x;
  const float* r = fin + (size_t)i * stride + off;
  float p0 = __fmul_rn(r[0], r[0]);
  float p1 = __fmul_rn(r[1], r[1]);
  float p2 = __fmul_rn(r[2], r[2]);
  sq[i] = __fadd_rn(__fadd_rn(p0, p1), p2);
}

// sq, C=64/128 (<=128): numpy pairwise 8-accumulator pattern, non-FMA.
template <int C>
__global__ void k_sqnorm_pw(const float* __restrict__ fin, int stride, int off,
                            float* __restrict__ sq) {
  int i = blockIdx.x * 256 + threadIdx.x;
  const float* r = fin + (size_t)i * stride + off;
  float a8[8];
  #pragma unroll
  for (int j = 0; j < 8; ++j) a8[j] = __fmul_rn(r[j], r[j]);
  #pragma unroll
  for (int ii = 8; ii < C; ii += 8)
    #pragma unroll
    for (int j = 0; j < 8; ++j)
      a8[j] = __fadd_rn(a8[j], __fmul_rn(r[ii + j], r[ii + j]));
  sq[i] = __fadd_rn(__fadd_rn(__fadd_rn(a8[0], a8[1]), __fadd_rn(a8[2], a8[3])),
                    __fadd_rn(__fadd_rn(a8[4], a8[5]), __fadd_rn(a8[6], a8[7])));
}

// ---------------------------------------------------------------------------
// Screen GEMM (sgemm-emulating): per-element single fmaf chain ascending k;
// D = (2e - sqn) - sqm left-assoc. 2 batches per dispatch.
__global__ void __launch_bounds__(256) k_screen(const float* __restrict__ fin,
                                                int stride, int off, int KK,
                                                const float* __restrict__ sq,
                                                int bbase, float* __restrict__ Dbase) {
  __shared__ float As[16][68];
  __shared__ float Bs[16][68];
  int tid = threadIdx.x;
  int b = bbase + blockIdx.z;
  float* D = Dbase + (size_t)blockIdx.z * NPTS * NPTS;
  int n0 = blockIdx.y * 64, m0 = blockIdx.x * 64;
  const float* fb = fin + (size_t)b * NPTS * stride + off;
  int lr = tid >> 2;            // 0..63
  int lk = (tid & 3) * 4;       // 0,4,8,12
  float acc[4][4];
  #pragma unroll
  for (int i = 0; i < 4; ++i)
    #pragma unroll
    for (int j = 0; j < 4; ++j) acc[i][j] = 0.f;
  for (int k0 = 0; k0 < KK; k0 += 16) {
    float4 av, bv;
    const float* arow = fb + (size_t)(n0 + lr) * stride + k0 + lk;
    const float* brow = fb + (size_t)(m0 + lr) * stride + k0 + lk;
    int rem = KK - k0;
    if (lk + 4 <= rem) { av = *(const float4*)arow; bv = *(const float4*)brow; }
    else {
      av.x = (lk + 0 < rem) ? arow[0] : 0.f;  bv.x = (lk + 0 < rem) ? brow[0] : 0.f;
      av.y = (lk + 1 < rem) ? arow[1] : 0.f;  bv.y = (lk + 1 < rem) ? brow[1] : 0.f;
      av.z = (lk + 2 < rem) ? arow[2] : 0.f;  bv.z = (lk + 2 < rem) ? brow[2] : 0.f;
      av.w = (lk + 3 < rem) ? arow[3] : 0.f;  bv.w = (lk + 3 < rem) ? brow[3] : 0.f;
    }
    __syncthreads();
    As[lk+0][lr] = av.x; As[lk+1][lr] = av.y; As[lk+2][lr] = av.z; As[lk+3][lr] = av.w;
    Bs[lk+0][lr] = bv.x; Bs[lk+1][lr] = bv.y; Bs[lk+2][lr] = bv.z; Bs[lk+3][lr] = bv.w;
    __syncthreads();
    int ty = tid >> 4, tx = tid & 15;
    #pragma unroll
    for (int kk = 0; kk < 16; ++kk) {
      float4 a = *(const float4*)&As[kk][ty * 4];
      float4 b2 = *(const float4*)&Bs[kk][tx * 4];
      acc[0][0] = fmaf(a.x, b2.x, acc[0][0]); acc[0][1] = fmaf(a.x, b2.y, acc[0][1]);
      acc[0][2] = fmaf(a.x, b2.z, acc[0][2]); acc[0][3] = fmaf(a.x, b2.w, acc[0][3]);
      acc[1][0] = fmaf(a.y, b2.x, acc[1][0]); acc[1][1] = fmaf(a.y, b2.y, acc[1][1]);
      acc[1][2] = fmaf(a.y, b2.z, acc[1][2]); acc[1][3] = fmaf(a.y, b2.w, acc[1][3]);
      acc[2][0] = fmaf(a.z, b2.x, acc[2][0]); acc[2][1] = fmaf(a.z, b2.y, acc[2][1]);
      acc[2][2] = fmaf(a.z, b2.z, acc[2][2]); acc[2][3] = fmaf(a.z, b2.w, acc[2][3]);
      acc[3][0] = fmaf(a.w, b2.x, acc[3][0]); acc[3][1] = fmaf(a.w, b2.y, acc[3][1]);
      acc[3][2] = fmaf(a.w, b2.z, acc[3][2]); acc[3][3] = fmaf(a.w, b2.w, acc[3][3]);
    }
  }
  int ty = tid >> 4, tx = tid & 15;
  const float* sqb = sq + b * NPTS;
  #pragma unroll
  for (int i = 0; i < 4; ++i) {
    float sn = sqb[n0 + ty * 4 + i];
    #pragma unroll
    for (int j = 0; j < 4; ++j) {
      float d = __fsub_rn(__fsub_rn(__fmul_rn(2.f, acc[i][j]), sn), sqb[m0 + tx * 4 + j]);
      D[(size_t)(n0 + ty * 4 + i) * NPTS + m0 + tx * 4 + j] = d;
    }
  }
}

// ---------------------------------------------------------------------------
__device__ inline unsigned f2u(float f) {
  unsigned b = __float_as_uint(f);
  return b ^ (unsigned)(((int)b >> 31) | 0x80000000);
}

// top-20 on f32 D: desc, ties -> lower index.
__device__ inline void row_select(const float (&dv)[32], int wt,
                                  int*   __restrict__ candc,   // [256]
                                  float* __restrict__ candf,   // [256]
                                  int* __restrict__ outp) {
  unsigned u[32];
  #pragma unroll
  for (int s = 0; s < 32; ++s) u[s] = f2u(dv[s]);
  unsigned P = 0u;
  for (int k = 31; k >= 8; --k) {
    unsigned Pt = P | (1u << k);
    int bc = 0;
    #pragma unroll
    for (int s = 0; s < 32; ++s) bc += (u[s] >= Pt) ? 1 : 0;
    #pragma unroll
    for (int o = 1; o < 64; o <<= 1) bc += __shfl_xor(bc, o, 64);
    if (bc >= 32) P = Pt;
  }
  const unsigned T = P;
  int cnt = 0;
  #pragma unroll
  for (int s = 0; s < 32; ++s) {
    bool pred = (u[s] >= T);
    unsigned long long mk = __ballot(pred);
    if (pred) {
      int pos = cnt + (int)__popcll(mk & ((1ull << wt) - 1ull));
      if (pos < 256) {
        candc[pos] = ((s >> 2) << 8) + (wt << 2) + (s & 3);
        candf[pos] = dv[s];
      }
    }
    cnt += (int)__popcll(mk);
  }
  if (cnt > 256) cnt = 256;
  __threadfence_block();
  #pragma unroll
  for (int q = 0; q < 4; ++q) {
    int ci = wt + 64 * q;
    if (ci < cnt) {
      int   mq = candc[ci];
      float dq = candf[ci];
      int r = 0;
      for (int j = 0; j < cnt; ++j) {
        float dj = candf[j]; int mj = candc[j];
        r += (dj > dq || (dj == dq && mj < mq)) ? 1 : 0;
      }
      if (r < KNN) outp[r] = mq;
    }
  }
}

__global__ void __launch_bounds__(256) k_select(const float* __restrict__ Dbase,
                                                int bbase, int* __restrict__ idxo) {
  __shared__ int   candcS[4][256];
  __shared__ float candfS[4][256];
  int tid = threadIdx.x;
  int wave = tid >> 6, wt = tid & 63;
  int b = bbase + blockIdx.y;
  const float* D = Dbase + (size_t)blockIdx.y * NPTS * NPTS;
  int n = blockIdx.x * 4 + wave;
  float dv[32];
  const float4* rp = (const float4*)(D + (size_t)n * NPTS) + wt;
  #pragma unroll
  for (int j = 0; j < 8; ++j) {
    float4 v = rp[64 * j];
    dv[j*4+0] = v.x; dv[j*4+1] = v.y; dv[j*4+2] = v.z; dv[j*4+3] = v.w;
  }
  row_select(dv, wt, candcS[wave], candfS[wave],
             idxo + ((size_t)b * NPTS + n) * KNN);
}

// ---------------------------------------------------------------------------
// Edge-conv layer 0 (2C=6): verified small kernel, kept as-is.
template <int C, int F>
__global__ void __launch_bounds__(256) k_econv(const float* __restrict__ fin,
                                               int stride, int off,
                                               const int* __restrict__ idx,
                                               const float* __restrict__ w,
                                               const float* __restrict__ g,
                                               float* __restrict__ cat, int catoff,
                                               double* __restrict__ stats) {
  const int TC = 2 * C;
  __shared__ float hS[20][2 * C + 4];
  __shared__ float wS[32][2 * C + 4];
  __shared__ float xnS[C];
  int tid = threadIdx.x;
  int n = blockIdx.x;
  int f0 = blockIdx.y * 32;
  int gbase = n & ~(NPTS - 1);
  for (int c = tid; c < C; c += 256) xnS[c] = fin[(size_t)n * stride + off + c];
  __syncthreads();
  for (int i = tid; i < 20 * C; i += 256) {
    int k = i / C, c = i - k * C;
    int m = idx[n * KNN + k];
    float xm = fin[(size_t)(gbase + m) * stride + off + c];
    hS[k][c] = __fsub_rn(xm, xnS[c]);
    hS[k][C + c] = xnS[c];
  }
  for (int i = tid; i < 32 * TC; i += 256) {
    int fr = i / TC, c = i - fr * TC;
    wS[fr][c] = w[(size_t)(f0 + fr) * TC + c];
  }
  __syncthreads();
  int f = tid >> 3, kl = tid & 7;      // 32 f x 8 k-lanes
  float mx = -1e30f, mn = 1e30f;
  double s = 0.0, ss = 0.0;
  for (int k = kl; k < KNN; k += 8) {
    float y = 0.f;
    #pragma unroll 8
    for (int c = 0; c < TC; ++c)
      y = fmaf(hS[k][c], wS[f][c], y);
    mx = fmaxf(mx, y); mn = fminf(mn, y);
    double yd = (double)y;
    s += yd; ss = fma(yd, yd, ss);
  }
  #pragma unroll
  for (int o = 4; o > 0; o >>= 1) {
    mx = fmaxf(mx, __shfl_down(mx, o, 8));
    mn = fminf(mn, __shfl_down(mn, o, 8));
    s += __shfl_down(s, o, 8);
    ss += __shfl_down(ss, o, 8);
  }
  if (kl == 0) {
    float gg = g[f0 + f];
    cat[(size_t)n * 512 + catoff + f0 + f] = (gg >= 0.f) ? mx : mn;
    atomicAdd(&stats[f0 + f], s);
    atomicAdd(&stats[F + f0 + f], ss);
  }
}

// ---------------------------------------------------------------------------
// w transpose: WT[c*F + f] = w[f*TC + c] (coalesced econv w loads).
__global__ void k_wt(const float* __restrict__ w, float* __restrict__ wt,
                     int TC, int F) {
  int i = blockIdx.x * 256 + threadIdx.x;
  if (i >= TC * F) return;
  int c = i / F, f = i - c * F;
  wt[i] = w[(size_t)f * TC + c];
}

// ---------------------------------------------------------------------------
// Edge-conv layers 1-3, GEMM-ified + f-block fused (bit-identical chains):
// (n,k) x 2C @ 2C x F as 64-row (3n x 20k interleaved + 4 pad) x (NFB x 64f)
// tiles, 4x4 register blocking per f-block, h gathered ONCE per n-block.
// Per-output chain: c0 outer, kk inner, ascending == verified semantics.
// LDS OVERLAY: yS (epilogue) aliases wS (main loop) — yS is only written
// after the last wS read, separated by __syncthreads. Cuts LDS 40->24 KB.
template <int C, int F, int NFB>
__global__ void __launch_bounds__(256) k_econv_g(const float* __restrict__ fin,
                                                 int stride, int off,
                                                 const int* __restrict__ idx,
                                                 const float* __restrict__ wt,  // [TC][F]
                                                 const float* __restrict__ g,
                                                 float* __restrict__ cat, int catoff,
                                                 double* __restrict__ stats) {
  const int TC = 2 * C;
  constexpr int WSZ = NFB * 16 * 68;
  constexpr int YSZ = 64 * 68;
  __shared__ float hS[16][68];
  __shared__ float wyS[(WSZ > YSZ) ? WSZ : YSZ];   // wS (main) / yS (epilogue)
  __shared__ float xnS[3 * C];
  __shared__ int   mS[64];
  int tid = threadIdx.x;
  int n0 = blockIdx.x * 3;           // 3 n's per block (rows = k*3+n)
  if (tid < 64) {
    int row = tid;
    int k = row / 3, n = row - 3 * k;
    int ng = n0 + n;
    mS[row] = (row < 60 && ng < BATCH * NPTS) ? idx[ng * KNN + k] : 0;
  }
  for (int i = tid; i < 3 * C; i += 256) {
    int n = i / C, c = i - n * C;
    int ng = n0 + n;
    xnS[i] = (ng < BATCH * NPTS) ? fin[(size_t)ng * stride + off + c] : 0.f;
  }
  __syncthreads();
  int ty = tid >> 4, tx = tid & 15;
  float acc[NFB][4][4];
  #pragma unroll
  for (int fb = 0; fb < NFB; ++fb)
    #pragma unroll
    for (int i = 0; i < 4; ++i)
      #pragma unroll
      for (int j = 0; j < 4; ++j) acc[fb][i][j] = 0.f;
  for (int c0 = 0; c0 < TC; c0 += 16) {
    float hv[4], wv[NFB][4];
    #pragma unroll
    for (int q = 0; q < 4; ++q) {
      int i = tid + 256 * q;           // 0..1023
      int row = i >> 4, cc = i & 15;
      int c = c0 + cc;
      float v = 0.f;
      if (row < 60) {
        int k = row / 3, n = row - 3 * k;
        (void)k;
        int ng = n0 + n;
        int gb = ng & ~(NPTS - 1);
        if (c < C) {
          float xm = fin[(size_t)(gb + mS[row]) * stride + off + c];
          v = __fsub_rn(xm, xnS[n * C + c]);
        } else {
          v = xnS[n * C + c - C];
        }
      }
      hv[q] = v;
      int kk = i >> 6, f = i & 63;     // 16 x 64
      #pragma unroll
      for (int fb = 0; fb < NFB; ++fb)
        wv[fb][q] = wt[(size_t)(c0 + kk) * F + fb * 64 + f];
    }
    __syncthreads();
    #pragma unroll
    for (int q = 0; q < 4; ++q) {
      int i = tid + 256 * q;
      hS[i & 15][i >> 4] = hv[q];
      #pragma unroll
      for (int fb = 0; fb < NFB; ++fb)
        wyS[(fb * 16 + (i >> 6)) * 68 + (i & 63)] = wv[fb][q];
    }
    __syncthreads();
    #pragma unroll
    for (int kk = 0; kk < 16; ++kk) {
      float4 a = *(const float4*)&hS[kk][ty * 4];
      #pragma unroll
      for (int fb = 0; fb < NFB; ++fb) {
        float4 b = *(const float4*)&wyS[(fb * 16 + kk) * 68 + tx * 4];
        acc[fb][0][0] = fmaf(a.x, b.x, acc[fb][0][0]); acc[fb][0][1] = fmaf(a.x, b.y, acc[fb][0][1]);
        acc[fb][0][2] = fmaf(a.x, b.z, acc[fb][0][2]); acc[fb][0][3] = fmaf(a.x, b.w, acc[fb][0][3]);
        acc[fb][1][0] = fmaf(a.y, b.x, acc[fb][1][0]); acc[fb][1][1] = fmaf(a.y, b.y, acc[fb][1][1]);
        acc[fb][1][2] = fmaf(a.y, b.z, acc[fb][1][2]); acc[fb][1][3] = fmaf(a.y, b.w, acc[fb][1][3]);
        acc[fb][2][0] = fmaf(a.z, b.x, acc[fb][2][0]); acc[fb][2][1] = fmaf(a.z, b.y, acc[fb][2][1]);
        acc[fb][2][2] = fmaf(a.z, b.z, acc[fb][2][2]); acc[fb][2][3] = fmaf(a.z, b.w, acc[fb][2][3]);
        acc[fb][3][0] = fmaf(a.w, b.x, acc[fb][3][0]); acc[fb][3][1] = fmaf(a.w, b.y, acc[fb][3][1]);
        acc[fb][3][2] = fmaf(a.w, b.z, acc[fb][3][2]); acc[fb][3][3] = fmaf(a.w, b.w, acc[fb][3][3]);
      }
    }
  }
  // Epilogue: per f-block, stage y-tile in wyS (overwrites wS — safe after
  // the barrier), reduce over k (fmax exact-assoc; f64 stats).
  #pragma unroll
  for (int fb = 0; fb < NFB; ++fb) {
    __syncthreads();
    #pragma unroll
    for (int i = 0; i < 4; ++i)
      #pragma unroll
      for (int j = 0; j < 4; ++j)
        wyS[(ty * 4 + i) * 68 + tx * 4 + j] = acc[fb][i][j];
    __syncthreads();
    if (tid < 192) {
      int n = tid >> 6, f = tid & 63;
      int ng = n0 + n;
      if (ng < BATCH * NPTS) {
        float mx = -1e30f, mn = 1e30f;
        double s = 0.0, ss = 0.0;
        #pragma unroll
        for (int k = 0; k < KNN; ++k) {
          float y = wyS[(k * 3 + n) * 68 + f];
          mx = fmaxf(mx, y); mn = fminf(mn, y);
          double yd = (double)y;
          s += yd; ss = fma(yd, yd, ss);
        }
        int fg = fb * 64 + f;
        float gg = g[fg];
        cat[(size_t)ng * 512 + catoff + fg] = (gg >= 0.f) ? mx : mn;
        atomicAdd(&stats[fg], s);
        atomicAdd(&stats[F + fg], ss);
      }
    }
  }
}

// BN + leaky on CAT slice: f64 stats, f32 left-assoc application.
__global__ void k_bn(float* __restrict__ cat, const double* __restrict__ stats,
                     const float* __restrict__ g, const float* __restrict__ bb,
                     int Fbits, int catoff) {
  int i = blockIdx.x * 256 + threadIdx.x;
  int F = 1 << Fbits;
  int f = i & (F - 1);
  int bn = i >> Fbits;
  const double invCnt = 1.0 / (double)(BATCH * NPTS * KNN);
  double mean64 = stats[f] * invCnt;
  double ex2 = stats[F + f] * invCnt;
  double var64 = ex2 - mean64 * mean64;
  if (var64 < 0.0) var64 = 0.0;
  float mean32 = (float)mean64;
  float vs = (float)var64;
  float rs = 1.0f / __fsqrt_rn(__fadd_rn(vs, 1e-5f));
  float* p = &cat[(size_t)bn * 512 + catoff + f];
  float y = *p;
  float u = __fmul_rn(g[f], __fsub_rn(y, mean32));
  float t = __fadd_rn(__fmul_rn(u, rs), bb[f]);
  *p = (t >= 0.f) ? t : __fmul_rn(0.2f, t);
}

// ---------------------------------------------------------------------------
// Final GEMM (values only; bf16-grid compare covers any k-order; we keep
// ascending fmaf anyway): 128x128 tile, 8x8 acc, BK=16.
__global__ void __launch_bounds__(256) k_gemm(const float* __restrict__ A,
                                              const float* __restrict__ Bw,
                                              float* __restrict__ Cc) {
  __shared__ float As[16][132];
  __shared__ float Bs[16][132];
  int tid = threadIdx.x;
  int m0 = blockIdx.y * 128, f0 = blockIdx.x * 128;
  int ty = tid >> 4, tx = tid & 15;
  int lr = tid >> 1;            // 0..127
  int lk = (tid & 1) * 8;       // 0,8
  float acc[8][8];
  #pragma unroll
  for (int i = 0; i < 8; ++i)
    #pragma unroll
    for (int j = 0; j < 8; ++j) acc[i][j] = 0.f;
  for (int k0 = 0; k0 < 512; k0 += 16) {
    float4 av0 = *(const float4*)&A [(size_t)(m0 + lr) * 512 + k0 + lk];
    float4 av1 = *(const float4*)&A [(size_t)(m0 + lr) * 512 + k0 + lk + 4];
    float4 bv0 = *(const float4*)&Bw[(size_t)(f0 + lr) * 512 + k0 + lk];
    float4 bv1 = *(const float4*)&Bw[(size_t)(f0 + lr) * 512 + k0 + lk + 4];
    __syncthreads();
    As[lk+0][lr] = av0.x; As[lk+1][lr] = av0.y; As[lk+2][lr] = av0.z; As[lk+3][lr] = av0.w;
    As[lk+4][lr] = av1.x; As[lk+5][lr] = av1.y; As[lk+6][lr] = av1.z; As[lk+7][lr] = av1.w;
    Bs[lk+0][lr] = bv0.x; Bs[lk+1][lr] = bv0.y; Bs[lk+2][lr] = bv0.z; Bs[lk+3][lr] = bv0.w;
    Bs[lk+4][lr] = bv1.x; Bs[lk+5][lr] = bv1.y; Bs[lk+6][lr] = bv1.z; Bs[lk+7][lr] = bv1.w;
    __syncthreads();
    #pragma unroll
    for (int kk = 0; kk < 16; ++kk) {
      float4 a0 = *(const float4*)&As[kk][ty * 8];
      float4 a1 = *(const float4*)&As[kk][ty * 8 + 4];
      float4 b0 = *(const float4*)&Bs[kk][tx * 8];
      float4 b1 = *(const float4*)&Bs[kk][tx * 8 + 4];
      float av[8] = {a0.x, a0.y, a0.z, a0.w, a1.x, a1.y, a1.z, a1.w};
      float bv[8] = {b0.x, b0.y, b0.z, b0.w, b1.x, b1.y, b1.z, b1.w};
      #pragma unroll
      for (int i = 0; i < 8; ++i)
        #pragma unroll
        for (int j = 0; j < 8; ++j)
          acc[i][j] = fmaf(av[i], bv[j], acc[i][j]);
    }
  }
  #pragma unroll
  for (int i = 0; i < 8; ++i) {
    float* orow = &Cc[(size_t)(m0 + ty * 8 + i) * 1024 + f0 + tx * 8];
    *(float4*)orow       = make_float4(acc[i][0], acc[i][1], acc[i][2], acc[i][3]);
    *(float4*)(orow + 4) = make_float4(acc[i][4], acc[i][5], acc[i][6], acc[i][7]);
  }
}

__global__ void k_fstats(const float* __restrict__ y, double* __restrict__ st) {
  int tid = threadIdx.x;
  int r0 = blockIdx.x * 256;
  double s[4] = {0,0,0,0}, ss[4] = {0,0,0,0};
  for (int r = r0; r < r0 + 256; ++r) {
    const float* row = y + (size_t)r * 1024;
    #pragma unroll
    for (int q = 0; q < 4; ++q) {
      double v = (double)row[tid + 256 * q];
      s[q] += v; ss[q] = fma(v, v, ss[q]);
    }
  }
  #pragma unroll
  for (int q = 0; q < 4; ++q) {
    atomicAdd(&st[tid + 256 * q], s[q]);
    atomicAdd(&st[1024 + tid + 256 * q], ss[q]);
  }
}

__global__ void k_fnorm(float* __restrict__ y, const double* __restrict__ st,
                        const float* __restrict__ g, const float* __restrict__ bb) {
  int i = blockIdx.x * 256 + threadIdx.x;
  int f = i & 1023;
  const double invCnt = 1.0 / 16384.0;
  double mean = st[f] * invCnt;
  double ex2  = st[1024 + f] * invCnt;
  double var  = ex2 - mean * mean;
  if (var < 0.0) var = 0.0;
  double rs   = rsqrt(var + 1e-5);
  float v = y[i];
  float t = (float)((double)g[f] * ((double)v - mean) * rs + (double)bb[f]);
  y[i] = (t >= 0.f) ? t : 0.2f * t;
}

// ---------------------------------------------------------------------------
extern "C" void kernel_launch(void* const* d_in, const int* in_sizes, int n_in,
                              void* d_out, int out_size, void* d_ws, size_t ws_size,
                              hipStream_t stream) {
  const float* x  = (const float*)d_in[0];
  const float* W[4]  = {(const float*)d_in[1], (const float*)d_in[4],
                        (const float*)d_in[7], (const float*)d_in[10]};
  const float* G[4]  = {(const float*)d_in[2], (const float*)d_in[5],
                        (const float*)d_in[8], (const float*)d_in[11]};
  const float* Bb[4] = {(const float*)d_in[3], (const float*)d_in[6],
                        (const float*)d_in[9], (const float*)d_in[12]};
  const float* wf = (const float*)d_in[13];
  const float* gf = (const float*)d_in[14];
  const float* bf = (const float*)d_in[15];
  float* out = (float*)d_out;

  // workspace: SQ, CAT, ZT (D scratch), ST (f64 stats), IDX, WT.
  float* ws  = (float*)d_ws;
  float* SQ  = ws;                 // 16384 f
  float* CAT = SQ + 16384;         // 8,388,608 f
  float* ZT  = CAT + 8388608;      // 8,388,608 f (D scratch, 2 batches)
  double* ST = (double*)(ZT + 8388608);    // 2048 d
  int*   IDX = (int*)(ST + 2048);  // 16384*20 ints
  float* WT  = (float*)(IDX + 16384 * KNN);  // 65,536 f (transposed w)

  const int Cs[4]      = {3, 64, 64, 128};
  const int Fs[4]      = {64, 64, 128, 256};
  const int Fbits[4]   = {6, 6, 7, 8};
  const int offs[4]    = {0, 0, 64, 128};
  const int strides[4] = {3, 512, 512, 512};
  const int catoffs[4] = {0, 64, 128, 256};
  const int NB3 = (BATCH * NPTS + 2) / 3;  // 5462 blocks of 3 n's

  for (int l = 0; l < 4; ++l) {
    const float* fin = (l == 0) ? x : CAT;
    int C = Cs[l], F = Fs[l];
    switch (C) {
      case 3:   k_sqnorm3<<<dim3(64), 256, 0, stream>>>(fin, strides[l], offs[l], SQ); break;
      case 64:  k_sqnorm_pw<64><<<dim3(64), 256, 0, stream>>>(fin, strides[l], offs[l], SQ); break;
      default:  k_sqnorm_pw<128><<<dim3(64), 256, 0, stream>>>(fin, strides[l], offs[l], SQ); break;
    }
    for (int bb = 0; bb < BATCH; bb += 2) {
      k_screen<<<dim3(NPTS / 64, NPTS / 64, 2), 256, 0, stream>>>(fin, strides[l], offs[l], C, SQ, bb, ZT);
      k_select<<<dim3(NPTS / 4, 2), 256, 0, stream>>>(ZT, bb, IDX);
    }
    (void)hipMemsetAsync(ST, 0, 2 * F * sizeof(double), stream);
    if (l > 0)
      k_wt<<<dim3((2 * C * F + 255) / 256), 256, 0, stream>>>(W[l], WT, 2 * C, F);
    switch (l) {
      case 0: k_econv<3, 64>        <<<dim3(16384, 2), 256, 0, stream>>>(fin, strides[l], offs[l], IDX, W[l], G[l], CAT, catoffs[l], ST); break;
      case 1: k_econv_g<64, 64, 1>  <<<dim3(NB3), 256, 0, stream>>>(fin, strides[l], offs[l], IDX, WT, G[l], CAT, catoffs[l], ST); break;
      case 2: k_econv_g<64, 128, 2> <<<dim3(NB3), 256, 0, stream>>>(fin, strides[l], offs[l], IDX, WT, G[l], CAT, catoffs[l], ST); break;
      default: k_econv_g<128, 256, 4><<<dim3(NB3), 256, 0, stream>>>(fin, strides[l], offs[l], IDX, WT, G[l], CAT, catoffs[l], ST); break;
    }
    k_bn<<<dim3(BATCH * NPTS * F / 256), 256, 0, stream>>>(CAT, ST, G[l], Bb[l], Fbits[l], catoffs[l]);
  }

  k_gemm<<<dim3(1024 / 128, 16384 / 128), 256, 0, stream>>>(CAT, wf, out);
  (void)hipMemsetAsync(ST, 0, 2048 * sizeof(double), stream);
  k_fstats<<<dim3(64), 256, 0, stream>>>(out, ST);
  k_fnorm<<<dim3(16384 * 1024 / 256), 256, 0, stream>>>(out, ST, gf, bf);
}

// Round 16
// 3235.915 us; speedup vs baseline: 2.0528x; 1.0127x over previous
//
#include <hip/hip_runtime.h>

#define NPTS 2048
#define BATCH 8
#define KNN 20

// ---------------------------------------------------------------------------
// Model (R0-R12, VERIFIED PASSING): ref = np transcription, einsum->sgemm
// (per-element ascending FMA chains), sq = multiply-temp + numpy pairwise
// non-FMA sum, d = (2e - sqn) - sqm left-assoc f32, top-k desc ties->lower
// index, conv = single FMA chain over concatenated 2C h-vector, BN f32
// left-assoc with f64 stats. Selection ranks on our f32 D.

// ---------------------------------------------------------------------------
// sq, C==3: products rounded individually, sequential sum (numpy n<8).
__global__ void k_sqnorm3(const float* __restrict__ fin, int stride, int off,
                          float* __restrict__ sq) {
  int i = blockIdx.x * 256 + threadIdx.x;
  const float* r = fin + (size_t)i * stride + off;
  float p0 = __fmul_rn(r[0], r[0]);
  float p1 = __fmul_rn(r[1], r[1]);
  float p2 = __fmul_rn(r[2], r[2]);
  sq[i] = __fadd_rn(__fadd_rn(p0, p1), p2);
}

// sq, C=64/128 (<=128): numpy pairwise 8-accumulator pattern, non-FMA.
template <int C>
__global__ void k_sqnorm_pw(const float* __restrict__ fin, int stride, int off,
                            float* __restrict__ sq) {
  int i = blockIdx.x * 256 + threadIdx.x;
  const float* r = fin + (size_t)i * stride + off;
  float a8[8];
  #pragma unroll
  for (int j = 0; j < 8; ++j) a8[j] = __fmul_rn(r[j], r[j]);
  #pragma unroll
  for (int ii = 8; ii < C; ii += 8)
    #pragma unroll
    for (int j = 0; j < 8; ++j)
      a8[j] = __fadd_rn(a8[j], __fmul_rn(r[ii + j], r[ii + j]));
  sq[i] = __fadd_rn(__fadd_rn(__fadd_rn(a8[0], a8[1]), __fadd_rn(a8[2], a8[3])),
                    __fadd_rn(__fadd_rn(a8[4], a8[5]), __fadd_rn(a8[6], a8[7])));
}

// ---------------------------------------------------------------------------
// Screen GEMM (sgemm-emulating): per-element single fmaf chain ascending k;
// D = (2e - sqn) - sqm left-assoc. 128x128 tile, 8x8/thread (4 fma/float).
__global__ void __launch_bounds__(256) k_screen(const float* __restrict__ fin,
                                                int stride, int off, int KK,
                                                const float* __restrict__ sq,
                                                int bbase, float* __restrict__ Dbase) {
  __shared__ float As[16][132];
  __shared__ float Bs[16][132];
  int tid = threadIdx.x;
  int b = bbase + blockIdx.z;
  float* D = Dbase + (size_t)blockIdx.z * NPTS * NPTS;
  int n0 = blockIdx.y * 128, m0 = blockIdx.x * 128;
  const float* fb = fin + (size_t)b * NPTS * stride + off;
  int lr = tid >> 1;            // 0..127
  int lk = (tid & 1) * 8;       // 0,8
  float acc[8][8];
  #pragma unroll
  for (int i = 0; i < 8; ++i)
    #pragma unroll
    for (int j = 0; j < 8; ++j) acc[i][j] = 0.f;
  for (int k0 = 0; k0 < KK; k0 += 16) {
    float av[8], bv[8];
    const float* arow = fb + (size_t)(n0 + lr) * stride + k0;
    const float* brow = fb + (size_t)(m0 + lr) * stride + k0;
    int rem = KK - k0;
    if (lk + 8 <= rem) {
      float4 a0 = *(const float4*)(arow + lk), a1 = *(const float4*)(arow + lk + 4);
      float4 b0 = *(const float4*)(brow + lk), b1 = *(const float4*)(brow + lk + 4);
      av[0]=a0.x; av[1]=a0.y; av[2]=a0.z; av[3]=a0.w; av[4]=a1.x; av[5]=a1.y; av[6]=a1.z; av[7]=a1.w;
      bv[0]=b0.x; bv[1]=b0.y; bv[2]=b0.z; bv[3]=b0.w; bv[4]=b1.x; bv[5]=b1.y; bv[6]=b1.z; bv[7]=b1.w;
    } else {
      #pragma unroll
      for (int j = 0; j < 8; ++j) {
        av[j] = (lk + j < rem) ? arow[lk + j] : 0.f;
        bv[j] = (lk + j < rem) ? brow[lk + j] : 0.f;
      }
    }
    __syncthreads();
    #pragma unroll
    for (int j = 0; j < 8; ++j) { As[lk + j][lr] = av[j]; Bs[lk + j][lr] = bv[j]; }
    __syncthreads();
    int ty = tid >> 4, tx = tid & 15;
    #pragma unroll
    for (int kk = 0; kk < 16; ++kk) {
      float4 a0 = *(const float4*)&As[kk][ty * 8];
      float4 a1 = *(const float4*)&As[kk][ty * 8 + 4];
      float4 b0 = *(const float4*)&Bs[kk][tx * 8];
      float4 b1 = *(const float4*)&Bs[kk][tx * 8 + 4];
      float aa[8] = {a0.x, a0.y, a0.z, a0.w, a1.x, a1.y, a1.z, a1.w};
      float bb[8] = {b0.x, b0.y, b0.z, b0.w, b1.x, b1.y, b1.z, b1.w};
      #pragma unroll
      for (int i = 0; i < 8; ++i)
        #pragma unroll
        for (int j = 0; j < 8; ++j)
          acc[i][j] = fmaf(aa[i], bb[j], acc[i][j]);
    }
  }
  int ty = tid >> 4, tx = tid & 15;
  const float* sqb = sq + b * NPTS;
  #pragma unroll
  for (int i = 0; i < 8; ++i) {
    float sn = sqb[n0 + ty * 8 + i];
    float* drow = &D[(size_t)(n0 + ty * 8 + i) * NPTS + m0 + tx * 8];
    #pragma unroll
    for (int j = 0; j < 8; ++j) {
      float d = __fsub_rn(__fsub_rn(__fmul_rn(2.f, acc[i][j]), sn), sqb[m0 + tx * 8 + j]);
      drow[j] = d;
    }
  }
}

// ---------------------------------------------------------------------------
__device__ inline unsigned f2u(float f) {
  unsigned b = __float_as_uint(f);
  return b ^ (unsigned)(((int)b >> 31) | 0x80000000);
}

// top-20 on f32 D: desc, ties -> lower index.
__device__ inline void row_select(const float (&dv)[32], int wt,
                                  int*   __restrict__ candc,   // [256]
                                  float* __restrict__ candf,   // [256]
                                  int* __restrict__ outp) {
  unsigned u[32];
  #pragma unroll
  for (int s = 0; s < 32; ++s) u[s] = f2u(dv[s]);
  unsigned P = 0u;
  for (int k = 31; k >= 8; --k) {
    unsigned Pt = P | (1u << k);
    int bc = 0;
    #pragma unroll
    for (int s = 0; s < 32; ++s) bc += (u[s] >= Pt) ? 1 : 0;
    #pragma unroll
    for (int o = 1; o < 64; o <<= 1) bc += __shfl_xor(bc, o, 64);
    if (bc >= 32) P = Pt;
  }
  const unsigned T = P;
  int cnt = 0;
  #pragma unroll
  for (int s = 0; s < 32; ++s) {
    bool pred = (u[s] >= T);
    unsigned long long mk = __ballot(pred);
    if (pred) {
      int pos = cnt + (int)__popcll(mk & ((1ull << wt) - 1ull));
      if (pos < 256) {
        candc[pos] = ((s >> 2) << 8) + (wt << 2) + (s & 3);
        candf[pos] = dv[s];
      }
    }
    cnt += (int)__popcll(mk);
  }
  if (cnt > 256) cnt = 256;
  __threadfence_block();
  #pragma unroll
  for (int q = 0; q < 4; ++q) {
    int ci = wt + 64 * q;
    if (ci < cnt) {
      int   mq = candc[ci];
      float dq = candf[ci];
      int r = 0;
      for (int j = 0; j < cnt; ++j) {
        float dj = candf[j]; int mj = candc[j];
        r += (dj > dq || (dj == dq && mj < mq)) ? 1 : 0;
      }
      if (r < KNN) outp[r] = mq;
    }
  }
}

__global__ void __launch_bounds__(256) k_select(const float* __restrict__ Dbase,
                                                int bbase, int* __restrict__ idxo) {
  __shared__ int   candcS[4][256];
  __shared__ float candfS[4][256];
  int tid = threadIdx.x;
  int wave = tid >> 6, wt = tid & 63;
  int b = bbase + blockIdx.y;
  const float* D = Dbase + (size_t)blockIdx.y * NPTS * NPTS;
  int n = blockIdx.x * 4 + wave;
  float dv[32];
  const float4* rp = (const float4*)(D + (size_t)n * NPTS) + wt;
  #pragma unroll
  for (int j = 0; j < 8; ++j) {
    float4 v = rp[64 * j];
    dv[j*4+0] = v.x; dv[j*4+1] = v.y; dv[j*4+2] = v.z; dv[j*4+3] = v.w;
  }
  row_select(dv, wt, candcS[wave], candfS[wave],
             idxo + ((size_t)b * NPTS + n) * KNN);
}

// ---------------------------------------------------------------------------
// Edge-conv layer 0 (2C=6): verified small kernel, kept as-is.
template <int C, int F>
__global__ void __launch_bounds__(256) k_econv(const float* __restrict__ fin,
                                               int stride, int off,
                                               const int* __restrict__ idx,
                                               const float* __restrict__ w,
                                               const float* __restrict__ g,
                                               float* __restrict__ cat, int catoff,
                                               double* __restrict__ stats) {
  const int TC = 2 * C;
  __shared__ float hS[20][2 * C + 4];
  __shared__ float wS[32][2 * C + 4];
  __shared__ float xnS[C];
  int tid = threadIdx.x;
  int n = blockIdx.x;
  int f0 = blockIdx.y * 32;
  int gbase = n & ~(NPTS - 1);
  for (int c = tid; c < C; c += 256) xnS[c] = fin[(size_t)n * stride + off + c];
  __syncthreads();
  for (int i = tid; i < 20 * C; i += 256) {
    int k = i / C, c = i - k * C;
    int m = idx[n * KNN + k];
    float xm = fin[(size_t)(gbase + m) * stride + off + c];
    hS[k][c] = __fsub_rn(xm, xnS[c]);
    hS[k][C + c] = xnS[c];
  }
  for (int i = tid; i < 32 * TC; i += 256) {
    int fr = i / TC, c = i - fr * TC;
    wS[fr][c] = w[(size_t)(f0 + fr) * TC + c];
  }
  __syncthreads();
  int f = tid >> 3, kl = tid & 7;      // 32 f x 8 k-lanes
  float mx = -1e30f, mn = 1e30f;
  double s = 0.0, ss = 0.0;
  for (int k = kl; k < KNN; k += 8) {
    float y = 0.f;
    #pragma unroll 8
    for (int c = 0; c < TC; ++c)
      y = fmaf(hS[k][c], wS[f][c], y);
    mx = fmaxf(mx, y); mn = fminf(mn, y);
    double yd = (double)y;
    s += yd; ss = fma(yd, yd, ss);
  }
  #pragma unroll
  for (int o = 4; o > 0; o >>= 1) {
    mx = fmaxf(mx, __shfl_down(mx, o, 8));
    mn = fminf(mn, __shfl_down(mn, o, 8));
    s += __shfl_down(s, o, 8);
    ss += __shfl_down(ss, o, 8);
  }
  if (kl == 0) {
    float gg = g[f0 + f];
    cat[(size_t)n * 512 + catoff + f0 + f] = (gg >= 0.f) ? mx : mn;
    atomicAdd(&stats[f0 + f], s);
    atomicAdd(&stats[F + f0 + f], ss);
  }
}

// ---------------------------------------------------------------------------
// w transpose: WT[c*F + f] = w[f*TC + c] (coalesced econv w loads).
__global__ void k_wt(const float* __restrict__ w, float* __restrict__ wt,
                     int TC, int F) {
  int i = blockIdx.x * 256 + threadIdx.x;
  if (i >= TC * F) return;
  int c = i / F, f = i - c * F;
  wt[i] = w[(size_t)f * TC + c];
}

// ---------------------------------------------------------------------------
// Edge-conv layers 1-3, GEMM-ified + f-block fused (bit-identical chains).
// TILE8: 8rows x 8f per thread (16 floats -> 64 fma, ratio 4.0) for NFB=4;
// else 4x4 per fb. Chain: c0 outer, kk inner, ascending == verified.
// LDS overlay: yS epilogue aliases wS.
template <int C, int F, int NFB, int TILE8>
__global__ void __launch_bounds__(256) k_econv_g(const float* __restrict__ fin,
                                                 int stride, int off,
                                                 const int* __restrict__ idx,
                                                 const float* __restrict__ wt,  // [TC][F]
                                                 const float* __restrict__ g,
                                                 float* __restrict__ cat, int catoff,
                                                 double* __restrict__ stats) {
  const int TC = 2 * C;
  constexpr int WSZ = NFB * 16 * 68;
  constexpr int YSZ = 64 * 68;
  __shared__ float hS[16][68];
  __shared__ float wyS[(WSZ > YSZ) ? WSZ : YSZ];   // wS (main) / yS (epilogue)
  __shared__ float xnS[3 * C];
  __shared__ int   mS[64];
  int tid = threadIdx.x;
  int n0 = blockIdx.x * 3;           // 3 n's per block (rows = k*3+n)
  if (tid < 64) {
    int row = tid;
    int k = row / 3, n = row - 3 * k;
    int ng = n0 + n;
    mS[row] = (row < 60 && ng < BATCH * NPTS) ? idx[ng * KNN + k] : 0;
  }
  for (int i = tid; i < 3 * C; i += 256) {
    int n = i / C, c = i - n * C;
    int ng = n0 + n;
    xnS[i] = (ng < BATCH * NPTS) ? fin[(size_t)ng * stride + off + c] : 0.f;
  }
  __syncthreads();
  float acc[TILE8 ? 64 : NFB * 16];
  #pragma unroll
  for (int i = 0; i < (TILE8 ? 64 : NFB * 16); ++i) acc[i] = 0.f;
  for (int c0 = 0; c0 < TC; c0 += 16) {
    float hv[4], wv[NFB][4];
    #pragma unroll
    for (int q = 0; q < 4; ++q) {
      int i = tid + 256 * q;           // 0..1023
      int row = i >> 4, cc = i & 15;
      int c = c0 + cc;
      float v = 0.f;
      if (row < 60) {
        int n = row - 3 * (row / 3);
        int ng = n0 + n;
        int gb = ng & ~(NPTS - 1);
        if (c < C) {
          float xm = fin[(size_t)(gb + mS[row]) * stride + off + c];
          v = __fsub_rn(xm, xnS[n * C + c]);
        } else {
          v = xnS[n * C + c - C];
        }
      }
      hv[q] = v;
      #pragma unroll
      for (int fb = 0; fb < NFB; ++fb)
        wv[fb][q] = wt[(size_t)(c0 + (i >> 6)) * F + fb * 64 + (i & 63)];
    }
    __syncthreads();
    #pragma unroll
    for (int q = 0; q < 4; ++q) {
      int i = tid + 256 * q;
      hS[i & 15][i >> 4] = hv[q];
      #pragma unroll
      for (int fb = 0; fb < NFB; ++fb)
        wyS[(fb * 16 + (i >> 6)) * 68 + (i & 63)] = wv[fb][q];
    }
    __syncthreads();
    if (TILE8) {
      // 8 rows x 8 f per thread: ty=tid>>5 (0..7), tx=tid&31; fb=tx>>3, fi=tx&7
      int ty = tid >> 5, tx = tid & 31;
      int fb = tx >> 3, fi = tx & 7;
      #pragma unroll
      for (int kk = 0; kk < 16; ++kk) {
        float4 a0 = *(const float4*)&hS[kk][ty * 8];
        float4 a1 = *(const float4*)&hS[kk][ty * 8 + 4];
        float4 b0 = *(const float4*)&wyS[(fb * 16 + kk) * 68 + fi * 8];
        float4 b1 = *(const float4*)&wyS[(fb * 16 + kk) * 68 + fi * 8 + 4];
        float aa[8] = {a0.x, a0.y, a0.z, a0.w, a1.x, a1.y, a1.z, a1.w};
        float bb[8] = {b0.x, b0.y, b0.z, b0.w, b1.x, b1.y, b1.z, b1.w};
        #pragma unroll
        for (int i = 0; i < 8; ++i)
          #pragma unroll
          for (int j = 0; j < 8; ++j)
            acc[i * 8 + j] = fmaf(aa[i], bb[j], acc[i * 8 + j]);
      }
    } else {
      int ty = tid >> 4, tx = tid & 15;
      #pragma unroll
      for (int kk = 0; kk < 16; ++kk) {
        float4 a = *(const float4*)&hS[kk][ty * 4];
        float aa[4] = {a.x, a.y, a.z, a.w};
        #pragma unroll
        for (int fb = 0; fb < NFB; ++fb) {
          float4 b = *(const float4*)&wyS[(fb * 16 + kk) * 68 + tx * 4];
          float bb[4] = {b.x, b.y, b.z, b.w};
          #pragma unroll
          for (int i = 0; i < 4; ++i)
            #pragma unroll
            for (int j = 0; j < 4; ++j)
              acc[fb * 16 + i * 4 + j] = fmaf(aa[i], bb[j], acc[fb * 16 + i * 4 + j]);
        }
      }
    }
  }
  // Epilogue: per f-block, stage y-tile in wyS (safe after barrier), reduce.
  #pragma unroll
  for (int fb = 0; fb < NFB; ++fb) {
    __syncthreads();
    if (TILE8) {
      int ty = tid >> 5, tx = tid & 31;
      if ((tx >> 3) == fb) {
        int fi = tx & 7;
        #pragma unroll
        for (int i = 0; i < 8; ++i)
          #pragma unroll
          for (int j = 0; j < 8; ++j)
            wyS[(ty * 8 + i) * 68 + fi * 8 + j] = acc[i * 8 + j];
      }
    } else {
      int ty = tid >> 4, tx = tid & 15;
      #pragma unroll
      for (int i = 0; i < 4; ++i)
        #pragma unroll
        for (int j = 0; j < 4; ++j)
          wyS[(ty * 4 + i) * 68 + tx * 4 + j] = acc[fb * 16 + i * 4 + j];
    }
    __syncthreads();
    if (tid < 192) {
      int n = tid >> 6, f = tid & 63;
      int ng = n0 + n;
      if (ng < BATCH * NPTS) {
        float mx = -1e30f, mn = 1e30f;
        double s = 0.0, ss = 0.0;
        #pragma unroll
        for (int k = 0; k < KNN; ++k) {
          float y = wyS[(k * 3 + n) * 68 + f];
          mx = fmaxf(mx, y); mn = fminf(mn, y);
          double yd = (double)y;
          s += yd; ss = fma(yd, yd, ss);
        }
        int fg = fb * 64 + f;
        float gg = g[fg];
        cat[(size_t)ng * 512 + catoff + fg] = (gg >= 0.f) ? mx : mn;
        atomicAdd(&stats[fg], s);
        atomicAdd(&stats[F + fg], ss);
      }
    }
  }
}

// BN + leaky on CAT slice: f64 stats, f32 left-assoc application.
__global__ void k_bn(float* __restrict__ cat, const double* __restrict__ stats,
                     const float* __restrict__ g, const float* __restrict__ bb,
                     int Fbits, int catoff) {
  int i = blockIdx.x * 256 + threadIdx.x;
  int F = 1 << Fbits;
  int f = i & (F - 1);
  int bn = i >> Fbits;
  const double invCnt = 1.0 / (double)(BATCH * NPTS * KNN);
  double mean64 = stats[f] * invCnt;
  double ex2 = stats[F + f] * invCnt;
  double var64 = ex2 - mean64 * mean64;
  if (var64 < 0.0) var64 = 0.0;
  float mean32 = (float)mean64;
  float vs = (float)var64;
  float rs = 1.0f / __fsqrt_rn(__fadd_rn(vs, 1e-5f));
  float* p = &cat[(size_t)bn * 512 + catoff + f];
  float y = *p;
  float u = __fmul_rn(g[f], __fsub_rn(y, mean32));
  float t = __fadd_rn(__fmul_rn(u, rs), bb[f]);
  *p = (t >= 0.f) ? t : __fmul_rn(0.2f, t);
}

// ---------------------------------------------------------------------------
// Final GEMM (values only): 128x128 tile, 8x8 acc, BK=16.
__global__ void __launch_bounds__(256) k_gemm(const float* __restrict__ A,
                                              const float* __restrict__ Bw,
                                              float* __restrict__ Cc) {
  __shared__ float As[16][132];
  __shared__ float Bs[16][132];
  int tid = threadIdx.x;
  int m0 = blockIdx.y * 128, f0 = blockIdx.x * 128;
  int ty = tid >> 4, tx = tid & 15;
  int lr = tid >> 1;            // 0..127
  int lk = (tid & 1) * 8;       // 0,8
  float acc[8][8];
  #pragma unroll
  for (int i = 0; i < 8; ++i)
    #pragma unroll
    for (int j = 0; j < 8; ++j) acc[i][j] = 0.f;
  for (int k0 = 0; k0 < 512; k0 += 16) {
    float4 av0 = *(const float4*)&A [(size_t)(m0 + lr) * 512 + k0 + lk];
    float4 av1 = *(const float4*)&A [(size_t)(m0 + lr) * 512 + k0 + lk + 4];
    float4 bv0 = *(const float4*)&Bw[(size_t)(f0 + lr) * 512 + k0 + lk];
    float4 bv1 = *(const float4*)&Bw[(size_t)(f0 + lr) * 512 + k0 + lk + 4];
    __syncthreads();
    As[lk+0][lr] = av0.x; As[lk+1][lr] = av0.y; As[lk+2][lr] = av0.z; As[lk+3][lr] = av0.w;
    As[lk+4][lr] = av1.x; As[lk+5][lr] = av1.y; As[lk+6][lr] = av1.z; As[lk+7][lr] = av1.w;
    Bs[lk+0][lr] = bv0.x; Bs[lk+1][lr] = bv0.y; Bs[lk+2][lr] = bv0.z; Bs[lk+3][lr] = bv0.w;
    Bs[lk+4][lr] = bv1.x; Bs[lk+5][lr] = bv1.y; Bs[lk+6][lr] = bv1.z; Bs[lk+7][lr] = bv1.w;
    __syncthreads();
    #pragma unroll
    for (int kk = 0; kk < 16; ++kk) {
      float4 a0 = *(const float4*)&As[kk][ty * 8];
      float4 a1 = *(const float4*)&As[kk][ty * 8 + 4];
      float4 b0 = *(const float4*)&Bs[kk][tx * 8];
      float4 b1 = *(const float4*)&Bs[kk][tx * 8 + 4];
      float av[8] = {a0.x, a0.y, a0.z, a0.w, a1.x, a1.y, a1.z, a1.w};
      float bv[8] = {b0.x, b0.y, b0.z, b0.w, b1.x, b1.y, b1.z, b1.w};
      #pragma unroll
      for (int i = 0; i < 8; ++i)
        #pragma unroll
        for (int j = 0; j < 8; ++j)
          acc[i][j] = fmaf(av[i], bv[j], acc[i][j]);
    }
  }
  #pragma unroll
  for (int i = 0; i < 8; ++i) {
    float* orow = &Cc[(size_t)(m0 + ty * 8 + i) * 1024 + f0 + tx * 8];
    *(float4*)orow       = make_float4(acc[i][0], acc[i][1], acc[i][2], acc[i][3]);
    *(float4*)(orow + 4) = make_float4(acc[i][4], acc[i][5], acc[i][6], acc[i][7]);
  }
}

__global__ void k_fstats(const float* __restrict__ y, double* __restrict__ st) {
  int tid = threadIdx.x;
  int r0 = blockIdx.x * 256;
  double s[4] = {0,0,0,0}, ss[4] = {0,0,0,0};
  for (int r = r0; r < r0 + 256; ++r) {
    const float* row = y + (size_t)r * 1024;
    #pragma unroll
    for (int q = 0; q < 4; ++q) {
      double v = (double)row[tid + 256 * q];
      s[q] += v; ss[q] = fma(v, v, ss[q]);
    }
  }
  #pragma unroll
  for (int q = 0; q < 4; ++q) {
    atomicAdd(&st[tid + 256 * q], s[q]);
    atomicAdd(&st[1024 + tid + 256 * q], ss[q]);
  }
}

__global__ void k_fnorm(float* __restrict__ y, const double* __restrict__ st,
                        const float* __restrict__ g, const float* __restrict__ bb) {
  int i = blockIdx.x * 256 + threadIdx.x;
  int f = i & 1023;
  const double invCnt = 1.0 / 16384.0;
  double mean = st[f] * invCnt;
  double ex2  = st[1024 + f] * invCnt;
  double var  = ex2 - mean * mean;
  if (var < 0.0) var = 0.0;
  double rs   = rsqrt(var + 1e-5);
  float v = y[i];
  float t = (float)((double)g[f] * ((double)v - mean) * rs + (double)bb[f]);
  y[i] = (t >= 0.f) ? t : 0.2f * t;
}

// ---------------------------------------------------------------------------
extern "C" void kernel_launch(void* const* d_in, const int* in_sizes, int n_in,
                              void* d_out, int out_size, void* d_ws, size_t ws_size,
                              hipStream_t stream) {
  const float* x  = (const float*)d_in[0];
  const float* W[4]  = {(const float*)d_in[1], (const float*)d_in[4],
                        (const float*)d_in[7], (const float*)d_in[10]};
  const float* G[4]  = {(const float*)d_in[2], (const float*)d_in[5],
                        (const float*)d_in[8], (const float*)d_in[11]};
  const float* Bb[4] = {(const float*)d_in[3], (const float*)d_in[6],
                        (const float*)d_in[9], (const float*)d_in[12]};
  const float* wf = (const float*)d_in[13];
  const float* gf = (const float*)d_in[14];
  const float* bf = (const float*)d_in[15];
  float* out = (float*)d_out;

  // workspace: SQ, CAT, ZT (D scratch), ST (f64 stats), IDX, WT.
  float* ws  = (float*)d_ws;
  float* SQ  = ws;                 // 16384 f
  float* CAT = SQ + 16384;         // 8,388,608 f
  float* ZT  = CAT + 8388608;      // 8,388,608 f (D scratch, 2 batches)
  double* ST = (double*)(ZT + 8388608);    // 2048 d
  int*   IDX = (int*)(ST + 2048);  // 16384*20 ints
  float* WT  = (float*)(IDX + 16384 * KNN);  // 65,536 f (transposed w)

  const int Cs[4]      = {3, 64, 64, 128};
  const int Fs[4]      = {64, 64, 128, 256};
  const int Fbits[4]   = {6, 6, 7, 8};
  const int offs[4]    = {0, 0, 64, 128};
  const int strides[4] = {3, 512, 512, 512};
  const int catoffs[4] = {0, 64, 128, 256};
  const int NB3 = (BATCH * NPTS + 2) / 3;  // 5462 blocks of 3 n's

  for (int l = 0; l < 4; ++l) {
    const float* fin = (l == 0) ? x : CAT;
    int C = Cs[l], F = Fs[l];
    switch (C) {
      case 3:   k_sqnorm3<<<dim3(64), 256, 0, stream>>>(fin, strides[l], offs[l], SQ); break;
      case 64:  k_sqnorm_pw<64><<<dim3(64), 256, 0, stream>>>(fin, strides[l], offs[l], SQ); break;
      default:  k_sqnorm_pw<128><<<dim3(64), 256, 0, stream>>>(fin, strides[l], offs[l], SQ); break;
    }
    for (int bb = 0; bb < BATCH; bb += 2) {
      k_screen<<<dim3(NPTS / 128, NPTS / 128, 2), 256, 0, stream>>>(fin, strides[l], offs[l], C, SQ, bb, ZT);
      k_select<<<dim3(NPTS / 4, 2), 256, 0, stream>>>(ZT, bb, IDX);
    }
    (void)hipMemsetAsync(ST, 0, 2 * F * sizeof(double), stream);
    if (l > 0)
      k_wt<<<dim3((2 * C * F + 255) / 256), 256, 0, stream>>>(W[l], WT, 2 * C, F);
    switch (l) {
      case 0: k_econv<3, 64>           <<<dim3(16384, 2), 256, 0, stream>>>(fin, strides[l], offs[l], IDX, W[l], G[l], CAT, catoffs[l], ST); break;
      case 1: k_econv_g<64, 64, 1, 0>  <<<dim3(NB3), 256, 0, stream>>>(fin, strides[l], offs[l], IDX, WT, G[l], CAT, catoffs[l], ST); break;
      case 2: k_econv_g<64, 128, 2, 0> <<<dim3(NB3), 256, 0, stream>>>(fin, strides[l], offs[l], IDX, WT, G[l], CAT, catoffs[l], ST); break;
      default: k_econv_g<128, 256, 4, 1><<<dim3(NB3), 256, 0, stream>>>(fin, strides[l], offs[l], IDX, WT, G[l], CAT, catoffs[l], ST); break;
    }
    k_bn<<<dim3(BATCH * NPTS * F / 256), 256, 0, stream>>>(CAT, ST, G[l], Bb[l], Fbits[l], catoffs[l]);
  }

  k_gemm<<<dim3(1024 / 128, 16384 / 128), 256, 0, stream>>>(CAT, wf, out);
  (void)hipMemsetAsync(ST, 0, 2048 * sizeof(double), stream);
  k_fstats<<<dim3(64), 256, 0, stream>>>(out, ST);
  k_fnorm<<<dim3(16384 * 1024 / 256), 256, 0, stream>>>(out, ST, gf, bf);
}